// Round 1
// baseline (2688.928 us; speedup 1.0000x reference)
//
#include <hip/hip_runtime.h>
#include <hip/hip_bf16.h>

// Model dims
#define EMB 512
#define NW  64
#define SEQ 65            // NW+1
#define NH  8
#define DH  64
#define NL  4
#define FF_ 2048
#define VOCAB 50257
#define BS  16
#define TOK (BS*SEQ)      // 1040
#define TOUT (BS*NW)      // 1024

// ---------------- embed: x[b,s,:] = (s==0?0:w_emb[b,s-1,:]) + word_enc[s,:]
__global__ void embed_kernel(const float* __restrict__ w_emb,
                             const float* __restrict__ word_enc,
                             float* __restrict__ x) {
    int idx = blockIdx.x * blockDim.x + threadIdx.x;
    const int total = BS * SEQ * EMB;
    if (idx >= total) return;
    int d = idx & (EMB - 1);
    int s = (idx >> 9) % SEQ;
    int b = idx / (SEQ * EMB);
    float we = word_enc[s * EMB + d];
    float e = (s == 0) ? 0.f : w_emb[((size_t)b * NW + (s - 1)) * EMB + d];
    x[idx] = e + we;
}

// ---------------- generic tiled GEMM: C[M,N] = A[M,K] * B[N,K]^T + bias, opt relu
#define BM 64
#define BN 64
#define BKK 32
__global__ __launch_bounds__(256) void gemm_nt(const float* __restrict__ A,
                                               const float* __restrict__ B,
                                               const float* __restrict__ bias,
                                               float* __restrict__ C,
                                               int M, int N, int K, int relu) {
    __shared__ float As[BKK][BM + 1];
    __shared__ float Bs[BKK][BN + 1];
    int t  = threadIdx.x;
    int m0 = blockIdx.y * BM;
    int n0 = blockIdx.x * BN;
    int tm = t >> 4, tn = t & 15;
    float c[4][4] = {};
    for (int k0 = 0; k0 < K; k0 += BKK) {
        #pragma unroll
        for (int i = 0; i < 2; ++i) {
            int li  = t + i * 256;
            int row = li >> 3, kq = li & 7;
            float4 v = make_float4(0.f, 0.f, 0.f, 0.f);
            int gr = m0 + row;
            if (gr < M) v = *(const float4*)(A + (size_t)gr * K + k0 + kq * 4);
            As[kq * 4 + 0][row] = v.x; As[kq * 4 + 1][row] = v.y;
            As[kq * 4 + 2][row] = v.z; As[kq * 4 + 3][row] = v.w;
        }
        #pragma unroll
        for (int i = 0; i < 2; ++i) {
            int li  = t + i * 256;
            int row = li >> 3, kq = li & 7;
            float4 v = make_float4(0.f, 0.f, 0.f, 0.f);
            int gr = n0 + row;
            if (gr < N) v = *(const float4*)(B + (size_t)gr * K + k0 + kq * 4);
            Bs[kq * 4 + 0][row] = v.x; Bs[kq * 4 + 1][row] = v.y;
            Bs[kq * 4 + 2][row] = v.z; Bs[kq * 4 + 3][row] = v.w;
        }
        __syncthreads();
        #pragma unroll
        for (int kk = 0; kk < BKK; ++kk) {
            float a[4], bb[4];
            #pragma unroll
            for (int i = 0; i < 4; ++i) a[i]  = As[kk][tm * 4 + i];
            #pragma unroll
            for (int j = 0; j < 4; ++j) bb[j] = Bs[kk][tn * 4 + j];
            #pragma unroll
            for (int i = 0; i < 4; ++i)
                #pragma unroll
                for (int j = 0; j < 4; ++j)
                    c[i][j] += a[i] * bb[j];
        }
        __syncthreads();
    }
    #pragma unroll
    for (int i = 0; i < 4; ++i) {
        int gm = m0 + tm * 4 + i;
        if (gm >= M) continue;
        #pragma unroll
        for (int j = 0; j < 4; ++j) {
            int gn = n0 + tn * 4 + j;
            if (gn >= N) continue;
            float v = c[i][j] + (bias ? bias[gn] : 0.f);
            if (relu) v = fmaxf(v, 0.f);
            C[(size_t)gm * N + gn] = v;
        }
    }
}

// ---------------- attention: one block per (q, h, b); S=65, dh=64
__global__ __launch_bounds__(128) void attn_kernel(const float* __restrict__ qkv,
                                                   float* __restrict__ ctx) {
    int qi = blockIdx.x, h = blockIdx.y, b = blockIdx.z;
    const float* base = qkv + (size_t)b * SEQ * (3 * EMB);
    __shared__ float qs[DH];
    __shared__ float sc[SEQ];
    __shared__ float red;
    int t = threadIdx.x;
    if (t < DH) qs[t] = base[(size_t)qi * (3 * EMB) + h * DH + t];
    __syncthreads();
    if (t < SEQ) {
        const float* krow = base + (size_t)t * (3 * EMB) + EMB + h * DH;
        float s = 0.f;
        #pragma unroll
        for (int d = 0; d < DH; ++d) s += qs[d] * krow[d];
        sc[t] = s * 0.125f;   // 1/sqrt(64)
    }
    __syncthreads();
    if (t == 0) {
        float m = -1e30f;
        for (int j = 0; j < SEQ; ++j) m = fmaxf(m, sc[j]);
        red = m;
    }
    __syncthreads();
    float m = red;
    if (t < SEQ) sc[t] = __expf(sc[t] - m);
    __syncthreads();
    if (t == 0) {
        float s = 0.f;
        for (int j = 0; j < SEQ; ++j) s += sc[j];
        red = 1.f / s;
    }
    __syncthreads();
    float inv = red;
    if (t < DH) {
        float acc = 0.f;
        for (int j = 0; j < SEQ; ++j)
            acc += sc[j] * base[(size_t)j * (3 * EMB) + 2 * EMB + h * DH + t];
        ctx[((size_t)b * SEQ + qi) * EMB + h * DH + t] = acc * inv;
    }
}

// ---------------- residual + layernorm: y = LN(x + p) * g + be   (row = token, EMB=512)
__global__ __launch_bounds__(128) void ln_kernel(const float* __restrict__ x,
                                                 const float* __restrict__ p,
                                                 const float* __restrict__ g,
                                                 const float* __restrict__ be,
                                                 float* __restrict__ y) {
    int row = blockIdx.x;
    int t = threadIdx.x;
    const float4 xv = ((const float4*)(x + (size_t)row * EMB))[t];
    const float4 pv = ((const float4*)(p + (size_t)row * EMB))[t];
    float v0 = xv.x + pv.x, v1 = xv.y + pv.y, v2 = xv.z + pv.z, v3 = xv.w + pv.w;
    float sum = v0 + v1 + v2 + v3;
    float sq  = v0 * v0 + v1 * v1 + v2 * v2 + v3 * v3;
    #pragma unroll
    for (int off = 32; off >= 1; off >>= 1) {
        sum += __shfl_down(sum, off);
        sq  += __shfl_down(sq,  off);
    }
    __shared__ float s0[2], s1[2];
    if ((t & 63) == 0) { s0[t >> 6] = sum; s1[t >> 6] = sq; }
    __syncthreads();
    float S = s0[0] + s0[1], Q = s1[0] + s1[1];
    float mean = S * (1.f / EMB);
    float var  = Q * (1.f / EMB) - mean * mean;
    float rstd = rsqrtf(var + 1e-5f);
    const float4 gv = ((const float4*)g)[t];
    const float4 bv = ((const float4*)be)[t];
    float4 o;
    o.x = (v0 - mean) * rstd * gv.x + bv.x;
    o.y = (v1 - mean) * rstd * gv.y + bv.y;
    o.z = (v2 - mean) * rstd * gv.z + bv.z;
    o.w = (v3 - mean) * rstd * gv.w + bv.w;
    ((float4*)(y + (size_t)row * EMB))[t] = o;
}

// ---------------- compact: xc[b,s,:] = x[b,s,:] for s in [0,64)  (drop s=64)
__global__ void compact_kernel(const float* __restrict__ x, float* __restrict__ xc) {
    int idx = blockIdx.x * blockDim.x + threadIdx.x;
    const int total = BS * NW * EMB;
    if (idx >= total) return;
    int d = idx & (EMB - 1);
    int s = (idx >> 9) & (NW - 1);
    int b = idx >> 15;
    xc[idx] = x[((size_t)b * SEQ + s) * EMB + d];
}

extern "C" void kernel_launch(void* const* d_in, const int* in_sizes, int n_in,
                              void* d_out, int out_size, void* d_ws, size_t ws_size,
                              hipStream_t stream) {
    const float* w_emb    = (const float*)d_in[0];
    const float* table    = (const float*)d_in[1];
    const float* word_enc = (const float*)d_in[2];
    const float* Wqkv     = (const float*)d_in[3];
    const float* bqkv     = (const float*)d_in[4];
    const float* Wo       = (const float*)d_in[5];
    const float* bo       = (const float*)d_in[6];
    const float* W1       = (const float*)d_in[7];
    const float* b1       = (const float*)d_in[8];
    const float* W2       = (const float*)d_in[9];
    const float* b2       = (const float*)d_in[10];
    const float* g1       = (const float*)d_in[11];
    const float* be1      = (const float*)d_in[12];
    const float* g2       = (const float*)d_in[13];
    const float* be2      = (const float*)d_in[14];
    float* out = (float*)d_out;

    // workspace layout (floats)
    float* ws = (float*)d_ws;
    float* xa   = ws;                          // TOK*EMB
    float* xb   = xa   + (size_t)TOK * EMB;    // TOK*EMB
    float* qkv  = xb   + (size_t)TOK * EMB;    // TOK*3*EMB
    float* ctx  = qkv  + (size_t)TOK * 3 * EMB;
    float* proj = ctx  + (size_t)TOK * EMB;
    float* hbuf = proj + (size_t)TOK * EMB;    // TOK*FF_
    float* xc   = hbuf + (size_t)TOK * FF_;    // TOUT*EMB

    // 1. embed
    {
        int total = BS * SEQ * EMB;
        embed_kernel<<<(total + 255) / 256, 256, 0, stream>>>(w_emb, word_enc, xa);
    }

    // 2. layers
    for (int l = 0; l < NL; ++l) {
        const float* Wqkv_l = Wqkv + (size_t)l * 3 * EMB * EMB;
        const float* bqkv_l = bqkv + (size_t)l * 3 * EMB;
        const float* Wo_l   = Wo   + (size_t)l * EMB * EMB;
        const float* bo_l   = bo   + (size_t)l * EMB;
        const float* W1_l   = W1   + (size_t)l * FF_ * EMB;
        const float* b1_l   = b1   + (size_t)l * FF_;
        const float* W2_l   = W2   + (size_t)l * EMB * FF_;
        const float* b2_l   = b2   + (size_t)l * EMB;

        // qkv = xa @ Wqkv^T + bqkv
        {
            dim3 grid((3 * EMB + BN - 1) / BN, (TOK + BM - 1) / BM);
            gemm_nt<<<grid, 256, 0, stream>>>(xa, Wqkv_l, bqkv_l, qkv, TOK, 3 * EMB, EMB, 0);
        }
        // attention
        {
            dim3 grid(SEQ, NH, BS);
            attn_kernel<<<grid, 128, 0, stream>>>(qkv, ctx);
        }
        // proj = ctx @ Wo^T + bo
        {
            dim3 grid((EMB + BN - 1) / BN, (TOK + BM - 1) / BM);
            gemm_nt<<<grid, 256, 0, stream>>>(ctx, Wo_l, bo_l, proj, TOK, EMB, EMB, 0);
        }
        // xb = LN(xa + proj)
        ln_kernel<<<TOK, 128, 0, stream>>>(xa, proj, g1 + (size_t)l * EMB, be1 + (size_t)l * EMB, xb);
        // hbuf = relu(xb @ W1^T + b1)
        {
            dim3 grid((FF_ + BN - 1) / BN, (TOK + BM - 1) / BM);
            gemm_nt<<<grid, 256, 0, stream>>>(xb, W1_l, b1_l, hbuf, TOK, FF_, EMB, 1);
        }
        // proj = hbuf @ W2^T + b2
        {
            dim3 grid((EMB + BN - 1) / BN, (TOK + BM - 1) / BM);
            gemm_nt<<<grid, 256, 0, stream>>>(hbuf, W2_l, b2_l, proj, TOK, EMB, FF_, 0);
        }
        // xa = LN(xb + proj)
        ln_kernel<<<TOK, 128, 0, stream>>>(xb, proj, g2 + (size_t)l * EMB, be2 + (size_t)l * EMB, xa);
    }

    // 3. compact + logits
    {
        int total = BS * NW * EMB;
        compact_kernel<<<(total + 255) / 256, 256, 0, stream>>>(xa, xc);
    }
    {
        dim3 grid((VOCAB + BN - 1) / BN, (TOUT + BM - 1) / BM);
        gemm_nt<<<grid, 256, 0, stream>>>(xc, table, nullptr, out, TOUT, VOCAB, EMB, 0);
    }
}

// Round 2
// 1195.907 us; speedup vs baseline: 2.2484x; 2.2484x over previous
//
#include <hip/hip_runtime.h>
#include <hip/hip_bf16.h>

// Model dims
#define EMB 512
#define NW  64
#define SEQ 65            // NW+1
#define NH  8
#define DH  64
#define NL  4
#define FF_ 2048
#define VOCAB 50257
#define BS  16
#define TOK (BS*SEQ)      // 1040
#define TOUT (BS*NW)      // 1024

typedef unsigned int u32;
typedef short short8  __attribute__((ext_vector_type(8)));   // 8 bf16 (A/B frag, 4 VGPRs)
typedef unsigned short ushort8 __attribute__((ext_vector_type(8)));
typedef float f32x4   __attribute__((ext_vector_type(4)));   // C/D frag

__device__ __forceinline__ unsigned short f2bf(float f) {
    unsigned u = __float_as_uint(f);
    return (unsigned short)((u + 0x7FFF + ((u >> 16) & 1)) >> 16);  // RNE
}
__device__ __forceinline__ float bf2f(unsigned short h) {
    return __uint_as_float(((unsigned)h) << 16);
}

// ---------------- embed: x[b,s,:] = (s==0?0:w_emb[b,s-1,:]) + word_enc[s,:]  (fp32 + bf16 out)
__global__ void embed_kernel(const float* __restrict__ w_emb,
                             const float* __restrict__ word_enc,
                             float* __restrict__ x32,
                             unsigned short* __restrict__ x16) {
    int idx = blockIdx.x * blockDim.x + threadIdx.x;
    const int total = BS * SEQ * EMB;
    if (idx >= total) return;
    int d = idx & (EMB - 1);
    int s = (idx >> 9) % SEQ;
    int b = idx / (SEQ * EMB);
    float we = word_enc[s * EMB + d];
    float e = (s == 0) ? 0.f : w_emb[((size_t)b * NW + (s - 1)) * EMB + d];
    float v = e + we;
    x32[idx] = v;
    x16[idx] = f2bf(v);
}

// ---------------- MFMA GEMM: C[M,N] = A[M,K](bf16) * B[N,K](fp32->bf16 inline)^T + bias
// 128x128 tile, BK=32, 256 threads = 4 waves (2x2), 4x4 16x16x32 frags per wave.
#define GBM 128
#define GBN 128
#define GBK 32

template<int OUT_BF16, int RELU>
__global__ __launch_bounds__(256) void gemm_bf(
    const unsigned short* __restrict__ A,   // [M,K] bf16
    const float*  __restrict__ B,           // [N,K] fp32 (weights)
    const float*  __restrict__ bias,        // [N] or null
    void* __restrict__ C,                   // [M,N] fp32 or bf16
    int M, int N, int K)
{
    __shared__ unsigned short As[GBM * GBK];   // 8 KB
    __shared__ unsigned short Bs[GBN * GBK];   // 8 KB
    int t = threadIdx.x;
    int w = t >> 6, l = t & 63;
    int m0 = blockIdx.y * GBM, n0 = blockIdx.x * GBN;
    int wr = w >> 1, wc = w & 1;

    f32x4 acc[4][4] = {};

    // B staging coords: row pair per thread
    int br = t >> 1, bh = t & 1;                 // row 0..127, k-half 0..1 (16 floats)
    int gbr = n0 + br; if (gbr >= N) gbr = N - 1;
    const float* bbase = B + (size_t)gbr * K + bh * 16;

    for (int kt = 0; kt < K; kt += GBK) {
        // ---- A tile via global_load_lds (16B/lane, 2 issues, linear LDS) ----
        #pragma unroll
        for (int i = 0; i < 2; ++i) {
            int tt = i * 256 + t;
            int row = tt >> 2, slot = tt & 3;
            int gr = m0 + row; if (gr >= M) gr = M - 1;
            const unsigned short* gp = A + (size_t)gr * K + kt + slot * 8;
            unsigned short* lp = As + (size_t)(i * 256 + w * 64) * 8;   // wave-uniform base
            __builtin_amdgcn_global_load_lds(
                (const __attribute__((address_space(1))) void*)gp,
                (__attribute__((address_space(3))) void*)lp, 16, 0, 0);
        }
        // ---- B tile: fp32 load -> bf16 convert -> ds_write ----
        {
            const float* bp = bbase + kt;
            float4 f0 = *(const float4*)(bp + 0);
            float4 f1 = *(const float4*)(bp + 4);
            float4 f2 = *(const float4*)(bp + 8);
            float4 f3 = *(const float4*)(bp + 12);
            ushort8 u0, u1;
            u0[0]=f2bf(f0.x); u0[1]=f2bf(f0.y); u0[2]=f2bf(f0.z); u0[3]=f2bf(f0.w);
            u0[4]=f2bf(f1.x); u0[5]=f2bf(f1.y); u0[6]=f2bf(f1.z); u0[7]=f2bf(f1.w);
            u1[0]=f2bf(f2.x); u1[1]=f2bf(f2.y); u1[2]=f2bf(f2.z); u1[3]=f2bf(f2.w);
            u1[4]=f2bf(f3.x); u1[5]=f2bf(f3.y); u1[6]=f2bf(f3.z); u1[7]=f2bf(f3.w);
            *(ushort8*)(Bs + br * GBK + bh * 16)     = u0;
            *(ushort8*)(Bs + br * GBK + bh * 16 + 8) = u1;
        }
        __syncthreads();   // drains vmcnt (global_load_lds) + lgkm (ds_write)

        // ---- 16 MFMA ----
        short8 af[4], bfr[4];
        #pragma unroll
        for (int mi = 0; mi < 4; ++mi)
            af[mi] = *(const short8*)(As + (size_t)(wr * 64 + mi * 16 + (l & 15)) * GBK + (l >> 4) * 8);
        #pragma unroll
        for (int ni = 0; ni < 4; ++ni)
            bfr[ni] = *(const short8*)(Bs + (size_t)(wc * 64 + ni * 16 + (l & 15)) * GBK + (l >> 4) * 8);
        #pragma unroll
        for (int mi = 0; mi < 4; ++mi)
            #pragma unroll
            for (int ni = 0; ni < 4; ++ni)
                acc[mi][ni] = __builtin_amdgcn_mfma_f32_16x16x32_bf16(af[mi], bfr[ni], acc[mi][ni], 0, 0, 0);
        __syncthreads();
    }

    // ---- epilogue: C[row][col], row=(l>>4)*4+r, col=l&15 within frag ----
    #pragma unroll
    for (int ni = 0; ni < 4; ++ni) {
        int col = n0 + wc * 64 + ni * 16 + (l & 15);
        if (col >= N) continue;
        float bv = bias ? bias[col] : 0.f;
        #pragma unroll
        for (int mi = 0; mi < 4; ++mi) {
            #pragma unroll
            for (int r = 0; r < 4; ++r) {
                int row = m0 + wr * 64 + mi * 16 + (l >> 4) * 4 + r;
                if (row >= M) continue;
                float v = acc[mi][ni][r] + bv;
                if (RELU) v = fmaxf(v, 0.f);
                if (OUT_BF16) ((unsigned short*)C)[(size_t)row * N + col] = f2bf(v);
                else          ((float*)C)[(size_t)row * N + col] = v;
            }
        }
    }
}

// ---------------- attention: one block per (q, h, b); S=65, dh=64; fp32 in, bf16 out
__global__ __launch_bounds__(128) void attn_kernel(const float* __restrict__ qkv,
                                                   unsigned short* __restrict__ ctx16) {
    int qi = blockIdx.x, h = blockIdx.y, b = blockIdx.z;
    const float* base = qkv + (size_t)b * SEQ * (3 * EMB);
    __shared__ float qs[DH];
    __shared__ float sc[SEQ];
    __shared__ float red;
    int t = threadIdx.x;
    if (t < DH) qs[t] = base[(size_t)qi * (3 * EMB) + h * DH + t];
    __syncthreads();
    if (t < SEQ) {
        const float* krow = base + (size_t)t * (3 * EMB) + EMB + h * DH;
        float s = 0.f;
        #pragma unroll
        for (int d = 0; d < DH; ++d) s += qs[d] * krow[d];
        sc[t] = s * 0.125f;
    }
    __syncthreads();
    if (t == 0) {
        float m = -1e30f;
        for (int j = 0; j < SEQ; ++j) m = fmaxf(m, sc[j]);
        red = m;
    }
    __syncthreads();
    float m = red;
    if (t < SEQ) sc[t] = __expf(sc[t] - m);
    __syncthreads();
    if (t == 0) {
        float s = 0.f;
        for (int j = 0; j < SEQ; ++j) s += sc[j];
        red = 1.f / s;
    }
    __syncthreads();
    float inv = red;
    if (t < DH) {
        float acc = 0.f;
        for (int j = 0; j < SEQ; ++j)
            acc += sc[j] * base[(size_t)j * (3 * EMB) + 2 * EMB + h * DH + t];
        ctx16[((size_t)b * SEQ + qi) * EMB + h * DH + t] = f2bf(acc * inv);
    }
}

// ---------------- residual + layernorm -> fp32 + bf16 outputs
__global__ __launch_bounds__(128) void ln_kernel(const float* __restrict__ x,
                                                 const float* __restrict__ p,
                                                 const float* __restrict__ g,
                                                 const float* __restrict__ be,
                                                 float* __restrict__ y32,
                                                 unsigned short* __restrict__ y16) {
    int row = blockIdx.x;
    int t = threadIdx.x;
    const float4 xv = ((const float4*)(x + (size_t)row * EMB))[t];
    const float4 pv = ((const float4*)(p + (size_t)row * EMB))[t];
    float v0 = xv.x + pv.x, v1 = xv.y + pv.y, v2 = xv.z + pv.z, v3 = xv.w + pv.w;
    float sum = v0 + v1 + v2 + v3;
    float sq  = v0 * v0 + v1 * v1 + v2 * v2 + v3 * v3;
    #pragma unroll
    for (int off = 32; off >= 1; off >>= 1) {
        sum += __shfl_down(sum, off);
        sq  += __shfl_down(sq,  off);
    }
    __shared__ float s0[2], s1[2];
    if ((t & 63) == 0) { s0[t >> 6] = sum; s1[t >> 6] = sq; }
    __syncthreads();
    float S = s0[0] + s0[1], Q = s1[0] + s1[1];
    float mean = S * (1.f / EMB);
    float var  = Q * (1.f / EMB) - mean * mean;
    float rstd = rsqrtf(var + 1e-5f);
    const float4 gv = ((const float4*)g)[t];
    const float4 bv = ((const float4*)be)[t];
    float4 o;
    o.x = (v0 - mean) * rstd * gv.x + bv.x;
    o.y = (v1 - mean) * rstd * gv.y + bv.y;
    o.z = (v2 - mean) * rstd * gv.z + bv.z;
    o.w = (v3 - mean) * rstd * gv.w + bv.w;
    ((float4*)(y32 + (size_t)row * EMB))[t] = o;
    ushort4 h;
    h.x = f2bf(o.x); h.y = f2bf(o.y); h.z = f2bf(o.z); h.w = f2bf(o.w);
    ((ushort4*)(y16 + (size_t)row * EMB))[t] = h;
}

// ---------------- compact (drop s=NW token): bf16 -> bf16
__global__ void compact_kernel(const unsigned short* __restrict__ x,
                               unsigned short* __restrict__ xc) {
    int idx = blockIdx.x * blockDim.x + threadIdx.x;
    const int total = BS * NW * EMB;
    if (idx >= total) return;
    int d = idx & (EMB - 1);
    int s = (idx >> 9) & (NW - 1);
    int b = idx >> 15;
    xc[idx] = x[((size_t)b * SEQ + s) * EMB + d];
}

extern "C" void kernel_launch(void* const* d_in, const int* in_sizes, int n_in,
                              void* d_out, int out_size, void* d_ws, size_t ws_size,
                              hipStream_t stream) {
    const float* w_emb    = (const float*)d_in[0];
    const float* table    = (const float*)d_in[1];
    const float* word_enc = (const float*)d_in[2];
    const float* Wqkv     = (const float*)d_in[3];
    const float* bqkv     = (const float*)d_in[4];
    const float* Wo       = (const float*)d_in[5];
    const float* bo       = (const float*)d_in[6];
    const float* W1       = (const float*)d_in[7];
    const float* b1       = (const float*)d_in[8];
    const float* W2       = (const float*)d_in[9];
    const float* b2       = (const float*)d_in[10];
    const float* g1       = (const float*)d_in[11];
    const float* be1      = (const float*)d_in[12];
    const float* g2       = (const float*)d_in[13];
    const float* be2      = (const float*)d_in[14];
    float* out = (float*)d_out;

    // workspace layout
    char* ws = (char*)d_ws;
    float* xa32  = (float*)ws;                    ws += (size_t)TOK * EMB * 4;
    float* xb32  = (float*)ws;                    ws += (size_t)TOK * EMB * 4;
    float* qkv32 = (float*)ws;                    ws += (size_t)TOK * 3 * EMB * 4;
    float* proj32= (float*)ws;                    ws += (size_t)TOK * EMB * 4;
    unsigned short* xa16  = (unsigned short*)ws;  ws += (size_t)TOK * EMB * 2;
    unsigned short* xb16  = (unsigned short*)ws;  ws += (size_t)TOK * EMB * 2;
    unsigned short* ctx16 = (unsigned short*)ws;  ws += (size_t)TOK * EMB * 2;
    unsigned short* hbuf16= (unsigned short*)ws;  ws += (size_t)TOK * FF_ * 2;
    unsigned short* xc16  = (unsigned short*)ws;  ws += (size_t)TOUT * EMB * 2;

    // 1. embed
    {
        int total = BS * SEQ * EMB;
        embed_kernel<<<(total + 255) / 256, 256, 0, stream>>>(w_emb, word_enc, xa32, xa16);
    }

    // 2. layers
    for (int l = 0; l < NL; ++l) {
        const float* Wqkv_l = Wqkv + (size_t)l * 3 * EMB * EMB;
        const float* bqkv_l = bqkv + (size_t)l * 3 * EMB;
        const float* Wo_l   = Wo   + (size_t)l * EMB * EMB;
        const float* bo_l   = bo   + (size_t)l * EMB;
        const float* W1_l   = W1   + (size_t)l * FF_ * EMB;
        const float* b1_l   = b1   + (size_t)l * FF_;
        const float* W2_l   = W2   + (size_t)l * EMB * FF_;
        const float* b2_l   = b2   + (size_t)l * EMB;

        // qkv = xa @ Wqkv^T + bqkv   (fp32 out)
        {
            dim3 grid((3 * EMB + GBN - 1) / GBN, (TOK + GBM - 1) / GBM);
            gemm_bf<0,0><<<grid, 256, 0, stream>>>(xa16, Wqkv_l, bqkv_l, qkv32, TOK, 3 * EMB, EMB);
        }
        // attention -> ctx16
        {
            dim3 grid(SEQ, NH, BS);
            attn_kernel<<<grid, 128, 0, stream>>>(qkv32, ctx16);
        }
        // proj = ctx @ Wo^T + bo  (fp32 out)
        {
            dim3 grid((EMB + GBN - 1) / GBN, (TOK + GBM - 1) / GBM);
            gemm_bf<0,0><<<grid, 256, 0, stream>>>(ctx16, Wo_l, bo_l, proj32, TOK, EMB, EMB);
        }
        // xb = LN(xa + proj)
        ln_kernel<<<TOK, 128, 0, stream>>>(xa32, proj32, g1 + (size_t)l * EMB, be1 + (size_t)l * EMB, xb32, xb16);
        // hbuf = relu(xb @ W1^T + b1)  (bf16 out)
        {
            dim3 grid((FF_ + GBN - 1) / GBN, (TOK + GBM - 1) / GBM);
            gemm_bf<1,1><<<grid, 256, 0, stream>>>(xb16, W1_l, b1_l, hbuf16, TOK, FF_, EMB);
        }
        // proj = hbuf @ W2^T + b2  (fp32 out)
        {
            dim3 grid((EMB + GBN - 1) / GBN, (TOK + GBM - 1) / GBM);
            gemm_bf<0,0><<<grid, 256, 0, stream>>>(hbuf16, W2_l, b2_l, proj32, TOK, EMB, FF_);
        }
        // xa = LN(xb + proj)
        ln_kernel<<<TOK, 128, 0, stream>>>(xb32, proj32, g2 + (size_t)l * EMB, be2 + (size_t)l * EMB, xa32, xa16);
    }

    // 3. compact + logits
    {
        int total = BS * NW * EMB;
        compact_kernel<<<(total + 255) / 256, 256, 0, stream>>>(xa16, xc16);
    }
    {
        dim3 grid((VOCAB + GBN - 1) / GBN, (TOUT + GBM - 1) / GBM);
        gemm_bf<0,0><<<grid, 256, 0, stream>>>(xc16, table, nullptr, out, TOUT, VOCAB, EMB);
    }
}

// Round 3
// 834.979 us; speedup vs baseline: 3.2204x; 1.4323x over previous
//
#include <hip/hip_runtime.h>
#include <hip/hip_bf16.h>

// Model dims
#define EMB 512
#define NW  64
#define SEQ 65            // NW+1
#define NH  8
#define DH  64
#define NL  4
#define FF_ 2048
#define VOCAB 50257
#define BS  16
#define TOK (BS*SEQ)      // 1040
#define TOUT (BS*NW)      // 1024

typedef short short8  __attribute__((ext_vector_type(8)));   // 8 bf16 (A/B frag)
typedef unsigned short ushort8n __attribute__((ext_vector_type(8)));
typedef float f32x4   __attribute__((ext_vector_type(4)));   // C/D frag

__device__ __forceinline__ unsigned short f2bf(float f) {
    unsigned u = __float_as_uint(f);
    return (unsigned short)((u + 0x7FFF + ((u >> 16) & 1)) >> 16);  // RNE
}

// ---------------- embed
__global__ void embed_kernel(const float* __restrict__ w_emb,
                             const float* __restrict__ word_enc,
                             float* __restrict__ x32,
                             unsigned short* __restrict__ x16) {
    int idx = blockIdx.x * blockDim.x + threadIdx.x;
    const int total = BS * SEQ * EMB;
    if (idx >= total) return;
    int d = idx & (EMB - 1);
    int s = (idx >> 9) % SEQ;
    int b = idx / (SEQ * EMB);
    float we = word_enc[s * EMB + d];
    float e = (s == 0) ? 0.f : w_emb[((size_t)b * NW + (s - 1)) * EMB + d];
    float v = e + we;
    x32[idx] = v;
    x16[idx] = f2bf(v);
}

// ---------------- MFMA GEMM: C[M,N] = A[M,K](bf16) * B[N,K](fp32->bf16 inline)^T + bias
// TM x TN tile, BK=32, 256 threads = 4 waves (2x2).
// LDS layout k-slot-major: granule(16B) index = slot*ROWS + row  -> conflict-free b128 frag reads.
// 2-phase double-buffered pipeline; LDS-transpose coalesced fp32 epilogue.
template<int TM, int TN, int OUT_BF16, int RELU, int COMPACT>
__global__ __launch_bounds__(256) void gemm2(const unsigned short* __restrict__ A,
                                             const float* __restrict__ B,
                                             const float* __restrict__ bias,
                                             void* __restrict__ C,
                                             int M, int N, int K) {
    constexpr int LTM = (TM == 128) ? 7 : 6;
    constexpr int FR  = TM / 32, FC = TN / 32;    // frags per wave dim
    constexpr int WRH = TM / 2,  WCH = TN / 2;    // wave tile span
    constexpr int AI  = TM / 64;                  // global_load_lds issues for A
    constexpr int TPR = 256 / TN;                 // threads per B row
    constexpr int SPT = 4 / TPR;                  // 8-elt k-slots per thread
    constexpr int STRIDE = (TM + TN) * 64;        // bytes per buffer (A + B)
    __shared__ __align__(16) char smem[2 * STRIDE];

    int t = threadIdx.x;
    int w = t >> 6, l = t & 63;
    int wr = w >> 1, wc = w & 1;
    int lr = l & 15, lh = l >> 4;
    int m0 = blockIdx.y * TM, n0 = blockIdx.x * TN;

    // B staging coords
    int br = t / TPR, bh = t % TPR;
    int gbr = n0 + br; if (gbr >= N) gbr = N - 1;
    const float* bbase = B + (size_t)gbr * K + bh * (SPT * 8);

    f32x4  acc[FR][FC] = {};
    float4 breg[TN / 32];

    const int nt = K >> 5;

    auto stageA = [&](int kt, int p) {
        char* dst = smem + p * STRIDE;
        #pragma unroll
        for (int i = 0; i < AI; ++i) {
            int tt   = i * 256 + t;
            int row  = tt & (TM - 1);
            int slot = tt >> LTM;
            int gr   = m0 + row;
            if (COMPACT) gr = ((gr >> 6) * SEQ) + (gr & 63);
            else if (gr >= M) gr = M - 1;
            const unsigned short* gp = A + (size_t)gr * K + kt + slot * 8;
            __builtin_amdgcn_global_load_lds(
                (const __attribute__((address_space(1))) void*)gp,
                (__attribute__((address_space(3))) void*)(dst + (size_t)(i * 256 + w * 64) * 16),
                16, 0, 0);
        }
    };
    auto loadB = [&](int kt) {
        const float* bp = bbase + kt;
        #pragma unroll
        for (int j = 0; j < TN / 32; ++j) breg[j] = *(const float4*)(bp + j * 4);
    };
    auto writeB = [&](int p) {
        unsigned short* bs = (unsigned short*)(smem + p * STRIDE + TM * 64);
        #pragma unroll
        for (int s = 0; s < SPT; ++s) {
            ushort8n u;
            #pragma unroll
            for (int e = 0; e < 8; ++e) {
                float f = ((const float*)&breg[s * 2 + (e >> 2)])[e & 3];
                u[e] = f2bf(f);
            }
            int slot = bh * SPT + s;
            *(ushort8n*)(bs + ((size_t)slot * TN + br) * 8) = u;
        }
    };
    auto compute = [&](int p) {
        const unsigned short* as_ = (const unsigned short*)(smem + p * STRIDE);
        const unsigned short* bs_ = as_ + TM * 32;
        short8 af[FR], bfv[FC];
        #pragma unroll
        for (int mi = 0; mi < FR; ++mi)
            af[mi] = *(const short8*)(as_ + ((size_t)lh * TM + wr * WRH + mi * 16 + lr) * 8);
        #pragma unroll
        for (int ni = 0; ni < FC; ++ni)
            bfv[ni] = *(const short8*)(bs_ + ((size_t)lh * TN + wc * WCH + ni * 16 + lr) * 8);
        #pragma unroll
        for (int mi = 0; mi < FR; ++mi)
            #pragma unroll
            for (int ni = 0; ni < FC; ++ni)
                acc[mi][ni] = __builtin_amdgcn_mfma_f32_16x16x32_bf16(af[mi], bfv[ni], acc[mi][ni], 0, 0, 0);
    };

    // prologue: stage tile 0
    stageA(0, 0);
    loadB(0);
    writeB(0);
    __syncthreads();

    for (int it = 0; it < nt; ++it) {
        int p = it & 1;
        if (it + 1 < nt) {             // issue next-tile loads BEFORE compute
            stageA((it + 1) << 5, 1 - p);
            loadB((it + 1) << 5);
        }
        compute(p);
        if (it + 1 < nt) writeB(1 - p);
        __syncthreads();               // drains gload_lds + ds_write; next tile ready
    }

    // ---- epilogue ----
    if (OUT_BF16) {
        #pragma unroll
        for (int ni = 0; ni < FC; ++ni) {
            int gcol = n0 + wc * WCH + ni * 16 + lr;
            if (gcol >= N) continue;
            float bv = bias ? bias[gcol] : 0.f;
            #pragma unroll
            for (int mi = 0; mi < FR; ++mi)
                #pragma unroll
                for (int r = 0; r < 4; ++r) {
                    int grow = m0 + wr * WRH + mi * 16 + lh * 4 + r;
                    if (grow >= M) continue;
                    float v = acc[mi][ni][r] + bv;
                    if (RELU) v = fmaxf(v, 0.f);
                    ((unsigned short*)C)[(size_t)grow * N + gcol] = f2bf(v);
                }
        }
    } else {
        constexpr int PAD = WCH + 4;                 // fp32 elems; keeps 16B alignment, spreads banks
        constexpr int CPR = WCH / 4;                 // float4 per row
        constexpr int J   = 16 * CPR / 64;
        float* ep = (float*)smem + (size_t)w * 16 * PAD;
        float bv[FC];
        #pragma unroll
        for (int ni = 0; ni < FC; ++ni) {
            int gcol = n0 + wc * WCH + ni * 16 + lr;
            bv[ni] = (bias && gcol < N) ? bias[gcol] : 0.f;
        }
        #pragma unroll
        for (int mi = 0; mi < FR; ++mi) {
            asm volatile("s_waitcnt lgkmcnt(0)" ::: "memory");   // prior reads of ep done
            #pragma unroll
            for (int ni = 0; ni < FC; ++ni)
                #pragma unroll
                for (int r = 0; r < 4; ++r) {
                    float v = acc[mi][ni][r] + bv[ni];
                    if (RELU) v = fmaxf(v, 0.f);
                    ep[(lh * 4 + r) * PAD + ni * 16 + lr] = v;
                }
            asm volatile("s_waitcnt lgkmcnt(0)" ::: "memory");
            __builtin_amdgcn_sched_barrier(0);
            #pragma unroll
            for (int j = 0; j < J; ++j) {
                int f4  = j * 64 + l;
                int row = f4 / CPR;
                int c4  = f4 % CPR;
                int grow = m0 + wr * WRH + mi * 16 + row;
                int gc   = n0 + wc * WCH + c4 * 4;
                if (grow < M) {
                    float4 v = *(const float4*)(ep + row * PAD + c4 * 4);
                    if (gc + 3 < N) {
                        *(float4*)((float*)C + (size_t)grow * N + gc) = v;
                    } else {
                        const float* pv = (const float*)&v;
                        #pragma unroll
                        for (int e = 0; e < 4; ++e)
                            if (gc + e < N) ((float*)C)[(size_t)grow * N + gc + e] = pv[e];
                    }
                }
            }
        }
    }
}

// ---------------- attention: one block per (q, h, b); S=65, dh=64; fp32 in, bf16 out
__global__ __launch_bounds__(128) void attn_kernel(const float* __restrict__ qkv,
                                                   unsigned short* __restrict__ ctx16) {
    int qi = blockIdx.x, h = blockIdx.y, b = blockIdx.z;
    const float* base = qkv + (size_t)b * SEQ * (3 * EMB);
    __shared__ float qs[DH];
    __shared__ float sc[SEQ];
    __shared__ float red;
    int t = threadIdx.x;
    if (t < DH) qs[t] = base[(size_t)qi * (3 * EMB) + h * DH + t];
    __syncthreads();
    if (t < SEQ) {
        const float* krow = base + (size_t)t * (3 * EMB) + EMB + h * DH;
        float s = 0.f;
        #pragma unroll
        for (int d = 0; d < DH; ++d) s += qs[d] * krow[d];
        sc[t] = s * 0.125f;
    }
    __syncthreads();
    if (t == 0) {
        float m = -1e30f;
        for (int j = 0; j < SEQ; ++j) m = fmaxf(m, sc[j]);
        red = m;
    }
    __syncthreads();
    float m = red;
    if (t < SEQ) sc[t] = __expf(sc[t] - m);
    __syncthreads();
    if (t == 0) {
        float s = 0.f;
        for (int j = 0; j < SEQ; ++j) s += sc[j];
        red = 1.f / s;
    }
    __syncthreads();
    float inv = red;
    if (t < DH) {
        float acc = 0.f;
        for (int j = 0; j < SEQ; ++j)
            acc += sc[j] * base[(size_t)j * (3 * EMB) + 2 * EMB + h * DH + t];
        ctx16[((size_t)b * SEQ + qi) * EMB + h * DH + t] = f2bf(acc * inv);
    }
}

// ---------------- residual + layernorm -> fp32 + bf16 outputs
__global__ __launch_bounds__(128) void ln_kernel(const float* __restrict__ x,
                                                 const float* __restrict__ p,
                                                 const float* __restrict__ g,
                                                 const float* __restrict__ be,
                                                 float* __restrict__ y32,
                                                 unsigned short* __restrict__ y16) {
    int row = blockIdx.x;
    int t = threadIdx.x;
    const float4 xv = ((const float4*)(x + (size_t)row * EMB))[t];
    const float4 pv = ((const float4*)(p + (size_t)row * EMB))[t];
    float v0 = xv.x + pv.x, v1 = xv.y + pv.y, v2 = xv.z + pv.z, v3 = xv.w + pv.w;
    float sum = v0 + v1 + v2 + v3;
    float sq  = v0 * v0 + v1 * v1 + v2 * v2 + v3 * v3;
    #pragma unroll
    for (int off = 32; off >= 1; off >>= 1) {
        sum += __shfl_down(sum, off);
        sq  += __shfl_down(sq,  off);
    }
    __shared__ float s0[2], s1[2];
    if ((t & 63) == 0) { s0[t >> 6] = sum; s1[t >> 6] = sq; }
    __syncthreads();
    float S = s0[0] + s0[1], Q = s1[0] + s1[1];
    float mean = S * (1.f / EMB);
    float var  = Q * (1.f / EMB) - mean * mean;
    float rstd = rsqrtf(var + 1e-5f);
    const float4 gv = ((const float4*)g)[t];
    const float4 bv = ((const float4*)be)[t];
    float4 o;
    o.x = (v0 - mean) * rstd * gv.x + bv.x;
    o.y = (v1 - mean) * rstd * gv.y + bv.y;
    o.z = (v2 - mean) * rstd * gv.z + bv.z;
    o.w = (v3 - mean) * rstd * gv.w + bv.w;
    ((float4*)(y32 + (size_t)row * EMB))[t] = o;
    ushort4 h;
    h.x = f2bf(o.x); h.y = f2bf(o.y); h.z = f2bf(o.z); h.w = f2bf(o.w);
    ((ushort4*)(y16 + (size_t)row * EMB))[t] = h;
}

extern "C" void kernel_launch(void* const* d_in, const int* in_sizes, int n_in,
                              void* d_out, int out_size, void* d_ws, size_t ws_size,
                              hipStream_t stream) {
    const float* w_emb    = (const float*)d_in[0];
    const float* table    = (const float*)d_in[1];
    const float* word_enc = (const float*)d_in[2];
    const float* Wqkv     = (const float*)d_in[3];
    const float* bqkv     = (const float*)d_in[4];
    const float* Wo       = (const float*)d_in[5];
    const float* bo       = (const float*)d_in[6];
    const float* W1       = (const float*)d_in[7];
    const float* b1       = (const float*)d_in[8];
    const float* W2       = (const float*)d_in[9];
    const float* b2       = (const float*)d_in[10];
    const float* g1       = (const float*)d_in[11];
    const float* be1      = (const float*)d_in[12];
    const float* g2       = (const float*)d_in[13];
    const float* be2      = (const float*)d_in[14];
    float* out = (float*)d_out;

    // workspace layout
    char* ws = (char*)d_ws;
    float* xa32  = (float*)ws;                    ws += (size_t)TOK * EMB * 4;
    float* xb32  = (float*)ws;                    ws += (size_t)TOK * EMB * 4;
    float* qkv32 = (float*)ws;                    ws += (size_t)TOK * 3 * EMB * 4;
    float* proj32= (float*)ws;                    ws += (size_t)TOK * EMB * 4;
    unsigned short* xa16  = (unsigned short*)ws;  ws += (size_t)TOK * EMB * 2;
    unsigned short* xb16  = (unsigned short*)ws;  ws += (size_t)TOK * EMB * 2;
    unsigned short* ctx16 = (unsigned short*)ws;  ws += (size_t)TOK * EMB * 2;
    unsigned short* hbuf16= (unsigned short*)ws;  ws += (size_t)TOK * FF_ * 2;

    // 1. embed
    {
        int total = BS * SEQ * EMB;
        embed_kernel<<<(total + 255) / 256, 256, 0, stream>>>(w_emb, word_enc, xa32, xa16);
    }

    // 2. layers
    for (int l = 0; l < NL; ++l) {
        const float* Wqkv_l = Wqkv + (size_t)l * 3 * EMB * EMB;
        const float* bqkv_l = bqkv + (size_t)l * 3 * EMB;
        const float* Wo_l   = Wo   + (size_t)l * EMB * EMB;
        const float* bo_l   = bo   + (size_t)l * EMB;
        const float* W1_l   = W1   + (size_t)l * FF_ * EMB;
        const float* b1_l   = b1   + (size_t)l * FF_;
        const float* W2_l   = W2   + (size_t)l * EMB * FF_;
        const float* b2_l   = b2   + (size_t)l * EMB;

        // qkv = xa @ Wqkv^T + bqkv
        gemm2<64,64,0,0,0><<<dim3((3 * EMB) / 64, (TOK + 63) / 64), 256, 0, stream>>>(
            xa16, Wqkv_l, bqkv_l, qkv32, TOK, 3 * EMB, EMB);
        // attention -> ctx16
        {
            dim3 grid(SEQ, NH, BS);
            attn_kernel<<<grid, 128, 0, stream>>>(qkv32, ctx16);
        }
        // proj = ctx @ Wo^T + bo
        gemm2<64,64,0,0,0><<<dim3(EMB / 64, (TOK + 63) / 64), 256, 0, stream>>>(
            ctx16, Wo_l, bo_l, proj32, TOK, EMB, EMB);
        // xb = LN(xa + proj)
        ln_kernel<<<TOK, 128, 0, stream>>>(xa32, proj32, g1 + (size_t)l * EMB, be1 + (size_t)l * EMB, xb32, xb16);
        // hbuf = relu(xb @ W1^T + b1)   (bf16 out)
        gemm2<64,64,1,1,0><<<dim3(FF_ / 64, (TOK + 63) / 64), 256, 0, stream>>>(
            xb16, W1_l, b1_l, hbuf16, TOK, FF_, EMB);
        // proj = hbuf @ W2^T + b2
        gemm2<64,64,0,0,0><<<dim3(EMB / 64, (TOK + 63) / 64), 256, 0, stream>>>(
            hbuf16, W2_l, b2_l, proj32, TOK, EMB, FF_);
        // xa = LN(xb + proj)
        ln_kernel<<<TOK, 128, 0, stream>>>(xb32, proj32, g2 + (size_t)l * EMB, be2 + (size_t)l * EMB, xa32, xa16);
    }

    // 3. logits (compact fused into A-stage row remap)
    gemm2<128,128,0,0,1><<<dim3((VOCAB + 127) / 128, TOUT / 128), 256, 0, stream>>>(
        xa16, table, nullptr, out, TOUT, VOCAB, EMB);
}

// Round 4
// 706.320 us; speedup vs baseline: 3.8070x; 1.1822x over previous
//
#include <hip/hip_runtime.h>
#include <hip/hip_bf16.h>

// Model dims
#define EMB 512
#define NW  64
#define SEQ 65            // NW+1
#define NH  8
#define DH  64
#define NL  4
#define FF_ 2048
#define VOCAB 50257
#define BS  16
#define TOK (BS*SEQ)      // 1040
#define TOUT (BS*NW)      // 1024

typedef short short8  __attribute__((ext_vector_type(8)));   // 8 bf16 (A/B frag)
typedef unsigned short ushort8n __attribute__((ext_vector_type(8)));
typedef float f32x4   __attribute__((ext_vector_type(4)));   // C/D frag

__device__ __forceinline__ unsigned short f2bf(float f) {
    unsigned u = __float_as_uint(f);
    return (unsigned short)((u + 0x7FFF + ((u >> 16) & 1)) >> 16);  // RNE
}

// ======== weight/table fp32 -> bf16 conversion (one pass, grid-stride) ========
#define SZ_WQKV (NL*3*EMB*EMB)          // 3,145,728
#define SZ_WO   (NL*EMB*EMB)            // 1,048,576
#define SZ_W1   (NL*FF_*EMB)            // 4,194,304
#define SZ_W2   (NL*EMB*FF_)            // 4,194,304
#define SZ_TAB  (VOCAB*EMB)             // 25,731,584
#define CVT_TOTAL (SZ_WQKV+SZ_WO+SZ_W1+SZ_W2+SZ_TAB)   // 38,314,496
#define O_WO   (SZ_WQKV)
#define O_W1   (O_WO+SZ_WO)
#define O_W2   (O_W1+SZ_W1)
#define O_TAB  (O_W2+SZ_W2)

__global__ void cvt_kernel(const float* __restrict__ wqkv, const float* __restrict__ wo,
                           const float* __restrict__ w1, const float* __restrict__ w2,
                           const float* __restrict__ table, unsigned short* __restrict__ dst) {
    const int U = CVT_TOTAL / 8;
    for (int u = blockIdx.x * blockDim.x + threadIdx.x; u < U; u += gridDim.x * blockDim.x) {
        size_t elem = (size_t)u * 8;
        const float* src; size_t loc = elem;
        if      (elem < O_WO)  { src = wqkv; }
        else if (elem < O_W1)  { src = wo;    loc = elem - O_WO; }
        else if (elem < O_W2)  { src = w1;    loc = elem - O_W1; }
        else if (elem < O_TAB) { src = w2;    loc = elem - O_W2; }
        else                   { src = table; loc = elem - O_TAB; }
        float4 f0 = *(const float4*)(src + loc);
        float4 f1 = *(const float4*)(src + loc + 4);
        ushort8n o;
        o[0]=f2bf(f0.x); o[1]=f2bf(f0.y); o[2]=f2bf(f0.z); o[3]=f2bf(f0.w);
        o[4]=f2bf(f1.x); o[5]=f2bf(f1.y); o[6]=f2bf(f1.z); o[7]=f2bf(f1.w);
        *(ushort8n*)(dst + elem) = o;
    }
}

// ---------------- embed
__global__ void embed_kernel(const float* __restrict__ w_emb,
                             const float* __restrict__ word_enc,
                             float* __restrict__ x32,
                             unsigned short* __restrict__ x16) {
    int idx = blockIdx.x * blockDim.x + threadIdx.x;
    const int total = BS * SEQ * EMB;
    if (idx >= total) return;
    int d = idx & (EMB - 1);
    int s = (idx >> 9) % SEQ;
    int b = idx / (SEQ * EMB);
    float we = word_enc[s * EMB + d];
    float e = (s == 0) ? 0.f : w_emb[((size_t)b * NW + (s - 1)) * EMB + d];
    float v = e + we;
    x32[idx] = v;
    x16[idx] = f2bf(v);
}

// ======== gemm3: C[M,N] = A[M,K](bf16) * B[N,K](bf16)^T + bias ========
// Both operands staged via global_load_lds (16B/lane) into k-slot-major LDS
// (granule idx = slot*ROWS + row -> conflict-free ds_read_b128 frag reads).
// 2-phase double-buffered pipeline. Grid: blockIdx.x = M-tile (row-fastest
// dispatch so blocks sharing a B panel are adjacent -> L2/L3 reuse).
template<int TM, int TN, int BK, int OUT_BF16, int RELU, int COMPACT>
__global__ __launch_bounds__(256) void gemm3(const unsigned short* __restrict__ A,
                                             const unsigned short* __restrict__ B,
                                             const float* __restrict__ bias,
                                             void* __restrict__ C,
                                             int M, int N, int K) {
    constexpr int LTM = (TM == 128) ? 7 : 6;
    constexpr int LTN = (TN == 128) ? 7 : 6;
    constexpr int FR  = TM / 32, FC = TN / 32;
    constexpr int WRH = TM / 2,  WCH = TN / 2;
    constexpr int KCH = BK / 32;                 // 32-wide k-chunks per iter
    constexpr int AI  = (TM * BK) / (8 * 256);   // gload_lds issues for A
    constexpr int BI  = (TN * BK) / (8 * 256);
    constexpr int ASZ = TM * BK * 2;             // bytes
    constexpr int STRIDE = (TM + TN) * BK * 2;
    __shared__ __align__(16) char smem[2 * STRIDE];

    int t = threadIdx.x;
    int w = t >> 6, l = t & 63;
    int wr = w >> 1, wc = w & 1;
    int lr = l & 15, lh = l >> 4;
    int m0 = blockIdx.x * TM, n0 = blockIdx.y * TN;

    f32x4 acc[FR][FC] = {};
    const int nt = K / BK;

    auto stageA = [&](int kt, int p) {
        char* dst = smem + p * STRIDE;
        #pragma unroll
        for (int i = 0; i < AI; ++i) {
            int tt = i * 256 + t;
            int row = tt & (TM - 1);
            int slot = tt >> LTM;
            int gr = m0 + row;
            if (COMPACT) gr = ((gr >> 6) * SEQ) + (gr & 63);
            else if (gr >= M) gr = M - 1;
            const unsigned short* gp = A + (size_t)gr * K + kt + slot * 8;
            __builtin_amdgcn_global_load_lds(
                (const __attribute__((address_space(1))) void*)gp,
                (__attribute__((address_space(3))) void*)(dst + (size_t)(i * 256 + w * 64) * 16),
                16, 0, 0);
        }
    };
    auto stageB = [&](int kt, int p) {
        char* dst = smem + p * STRIDE + ASZ;
        #pragma unroll
        for (int i = 0; i < BI; ++i) {
            int tt = i * 256 + t;
            int row = tt & (TN - 1);
            int slot = tt >> LTN;
            int gr = n0 + row;
            if (gr >= N) gr = N - 1;
            const unsigned short* gp = B + (size_t)gr * K + kt + slot * 8;
            __builtin_amdgcn_global_load_lds(
                (const __attribute__((address_space(1))) void*)gp,
                (__attribute__((address_space(3))) void*)(dst + (size_t)(i * 256 + w * 64) * 16),
                16, 0, 0);
        }
    };
    auto compute = [&](int p) {
        const unsigned short* as_ = (const unsigned short*)(smem + p * STRIDE);
        const unsigned short* bs_ = as_ + TM * BK;
        #pragma unroll
        for (int kk = 0; kk < KCH; ++kk) {
            short8 af[FR], bfv[FC];
            #pragma unroll
            for (int mi = 0; mi < FR; ++mi)
                af[mi] = *(const short8*)(as_ + ((size_t)(kk * 4 + lh) * TM + wr * WRH + mi * 16 + lr) * 8);
            #pragma unroll
            for (int ni = 0; ni < FC; ++ni)
                bfv[ni] = *(const short8*)(bs_ + ((size_t)(kk * 4 + lh) * TN + wc * WCH + ni * 16 + lr) * 8);
            #pragma unroll
            for (int mi = 0; mi < FR; ++mi)
                #pragma unroll
                for (int ni = 0; ni < FC; ++ni)
                    acc[mi][ni] = __builtin_amdgcn_mfma_f32_16x16x32_bf16(af[mi], bfv[ni], acc[mi][ni], 0, 0, 0);
        }
    };

    stageA(0, 0);
    stageB(0, 0);
    __syncthreads();
    for (int it = 0; it < nt; ++it) {
        int p = it & 1;
        if (it + 1 < nt) {              // issue next-tile DMA before compute
            stageA((it + 1) * BK, 1 - p);
            stageB((it + 1) * BK, 1 - p);
        }
        compute(p);
        __syncthreads();                // drains vmcnt -> next tile ready
    }

    // ---- epilogue ----
    if (OUT_BF16) {
        #pragma unroll
        for (int ni = 0; ni < FC; ++ni) {
            int gcol = n0 + wc * WCH + ni * 16 + lr;
            if (gcol >= N) continue;
            float bv = bias ? bias[gcol] : 0.f;
            #pragma unroll
            for (int mi = 0; mi < FR; ++mi)
                #pragma unroll
                for (int r = 0; r < 4; ++r) {
                    int grow = m0 + wr * WRH + mi * 16 + lh * 4 + r;
                    if (grow >= M) continue;
                    float v = acc[mi][ni][r] + bv;
                    if (RELU) v = fmaxf(v, 0.f);
                    ((unsigned short*)C)[(size_t)grow * N + gcol] = f2bf(v);
                }
        }
    } else {
        constexpr int PAD = WCH + 4;
        constexpr int CPR = WCH / 4;
        constexpr int J   = 16 * CPR / 64;
        float* ep = (float*)smem + (size_t)w * 16 * PAD;
        float bv[FC];
        #pragma unroll
        for (int ni = 0; ni < FC; ++ni) {
            int gcol = n0 + wc * WCH + ni * 16 + lr;
            bv[ni] = (bias && gcol < N) ? bias[gcol] : 0.f;
        }
        #pragma unroll
        for (int mi = 0; mi < FR; ++mi) {
            asm volatile("s_waitcnt lgkmcnt(0)" ::: "memory");
            #pragma unroll
            for (int ni = 0; ni < FC; ++ni)
                #pragma unroll
                for (int r = 0; r < 4; ++r) {
                    float v = acc[mi][ni][r] + bv[ni];
                    if (RELU) v = fmaxf(v, 0.f);
                    ep[(lh * 4 + r) * PAD + ni * 16 + lr] = v;
                }
            asm volatile("s_waitcnt lgkmcnt(0)" ::: "memory");
            __builtin_amdgcn_sched_barrier(0);
            #pragma unroll
            for (int j = 0; j < J; ++j) {
                int f4  = j * 64 + l;
                int row = f4 / CPR;
                int c4  = f4 % CPR;
                int grow = m0 + wr * WRH + mi * 16 + row;
                int gc   = n0 + wc * WCH + c4 * 4;
                if (grow < M) {
                    float4 v = *(const float4*)(ep + row * PAD + c4 * 4);
                    if (gc + 3 < N) {
                        *(float4*)((float*)C + (size_t)grow * N + gc) = v;
                    } else {
                        const float* pv = (const float*)&v;
                        #pragma unroll
                        for (int e = 0; e < 4; ++e)
                            if (gc + e < N) ((float*)C)[(size_t)grow * N + gc + e] = pv[e];
                    }
                }
            }
        }
    }
}

// ======== gemm2 (round-3 fallback: B fp32 inline-converted) ========
template<int TM, int TN, int OUT_BF16, int RELU, int COMPACT>
__global__ __launch_bounds__(256) void gemm2(const unsigned short* __restrict__ A,
                                             const float* __restrict__ B,
                                             const float* __restrict__ bias,
                                             void* __restrict__ C,
                                             int M, int N, int K) {
    constexpr int LTM = (TM == 128) ? 7 : 6;
    constexpr int FR  = TM / 32, FC = TN / 32;
    constexpr int WRH = TM / 2,  WCH = TN / 2;
    constexpr int AI  = TM / 64;
    constexpr int TPR = 256 / TN;
    constexpr int SPT = 4 / TPR;
    constexpr int STRIDE = (TM + TN) * 64;
    __shared__ __align__(16) char smem[2 * STRIDE];

    int t = threadIdx.x;
    int w = t >> 6, l = t & 63;
    int wr = w >> 1, wc = w & 1;
    int lr = l & 15, lh = l >> 4;
    int m0 = blockIdx.y * TM, n0 = blockIdx.x * TN;

    int br = t / TPR, bh = t % TPR;
    int gbr = n0 + br; if (gbr >= N) gbr = N - 1;
    const float* bbase = B + (size_t)gbr * K + bh * (SPT * 8);

    f32x4  acc[FR][FC] = {};
    float4 breg[TN / 32];
    const int nt = K >> 5;

    auto stageA = [&](int kt, int p) {
        char* dst = smem + p * STRIDE;
        #pragma unroll
        for (int i = 0; i < AI; ++i) {
            int tt   = i * 256 + t;
            int row  = tt & (TM - 1);
            int slot = tt >> LTM;
            int gr   = m0 + row;
            if (COMPACT) gr = ((gr >> 6) * SEQ) + (gr & 63);
            else if (gr >= M) gr = M - 1;
            const unsigned short* gp = A + (size_t)gr * K + kt + slot * 8;
            __builtin_amdgcn_global_load_lds(
                (const __attribute__((address_space(1))) void*)gp,
                (__attribute__((address_space(3))) void*)(dst + (size_t)(i * 256 + w * 64) * 16),
                16, 0, 0);
        }
    };
    auto loadB = [&](int kt) {
        const float* bp = bbase + kt;
        #pragma unroll
        for (int j = 0; j < TN / 32; ++j) breg[j] = *(const float4*)(bp + j * 4);
    };
    auto writeB = [&](int p) {
        unsigned short* bs = (unsigned short*)(smem + p * STRIDE + TM * 64);
        #pragma unroll
        for (int s = 0; s < SPT; ++s) {
            ushort8n u;
            #pragma unroll
            for (int e = 0; e < 8; ++e) {
                float f = ((const float*)&breg[s * 2 + (e >> 2)])[e & 3];
                u[e] = f2bf(f);
            }
            int slot = bh * SPT + s;
            *(ushort8n*)(bs + ((size_t)slot * TN + br) * 8) = u;
        }
    };
    auto compute = [&](int p) {
        const unsigned short* as_ = (const unsigned short*)(smem + p * STRIDE);
        const unsigned short* bs_ = as_ + TM * 32;
        short8 af[FR], bfv[FC];
        #pragma unroll
        for (int mi = 0; mi < FR; ++mi)
            af[mi] = *(const short8*)(as_ + ((size_t)lh * TM + wr * WRH + mi * 16 + lr) * 8);
        #pragma unroll
        for (int ni = 0; ni < FC; ++ni)
            bfv[ni] = *(const short8*)(bs_ + ((size_t)lh * TN + wc * WCH + ni * 16 + lr) * 8);
        #pragma unroll
        for (int mi = 0; mi < FR; ++mi)
            #pragma unroll
            for (int ni = 0; ni < FC; ++ni)
                acc[mi][ni] = __builtin_amdgcn_mfma_f32_16x16x32_bf16(af[mi], bfv[ni], acc[mi][ni], 0, 0, 0);
    };

    stageA(0, 0); loadB(0); writeB(0);
    __syncthreads();
    for (int it = 0; it < nt; ++it) {
        int p = it & 1;
        if (it + 1 < nt) { stageA((it + 1) << 5, 1 - p); loadB((it + 1) << 5); }
        compute(p);
        if (it + 1 < nt) writeB(1 - p);
        __syncthreads();
    }

    if (OUT_BF16) {
        #pragma unroll
        for (int ni = 0; ni < FC; ++ni) {
            int gcol = n0 + wc * WCH + ni * 16 + lr;
            if (gcol >= N) continue;
            float bv = bias ? bias[gcol] : 0.f;
            #pragma unroll
            for (int mi = 0; mi < FR; ++mi)
                #pragma unroll
                for (int r = 0; r < 4; ++r) {
                    int grow = m0 + wr * WRH + mi * 16 + lh * 4 + r;
                    if (grow >= M) continue;
                    float v = acc[mi][ni][r] + bv;
                    if (RELU) v = fmaxf(v, 0.f);
                    ((unsigned short*)C)[(size_t)grow * N + gcol] = f2bf(v);
                }
        }
    } else {
        constexpr int PAD = WCH + 4;
        constexpr int CPR = WCH / 4;
        constexpr int J   = 16 * CPR / 64;
        float* ep = (float*)smem + (size_t)w * 16 * PAD;
        float bv[FC];
        #pragma unroll
        for (int ni = 0; ni < FC; ++ni) {
            int gcol = n0 + wc * WCH + ni * 16 + lr;
            bv[ni] = (bias && gcol < N) ? bias[gcol] : 0.f;
        }
        #pragma unroll
        for (int mi = 0; mi < FR; ++mi) {
            asm volatile("s_waitcnt lgkmcnt(0)" ::: "memory");
            #pragma unroll
            for (int ni = 0; ni < FC; ++ni)
                #pragma unroll
                for (int r = 0; r < 4; ++r) {
                    float v = acc[mi][ni][r] + bv[ni];
                    if (RELU) v = fmaxf(v, 0.f);
                    ep[(lh * 4 + r) * PAD + ni * 16 + lr] = v;
                }
            asm volatile("s_waitcnt lgkmcnt(0)" ::: "memory");
            __builtin_amdgcn_sched_barrier(0);
            #pragma unroll
            for (int j = 0; j < J; ++j) {
                int f4  = j * 64 + l;
                int row = f4 / CPR;
                int c4  = f4 % CPR;
                int grow = m0 + wr * WRH + mi * 16 + row;
                int gc   = n0 + wc * WCH + c4 * 4;
                if (grow < M) {
                    float4 v = *(const float4*)(ep + row * PAD + c4 * 4);
                    if (gc + 3 < N) {
                        *(float4*)((float*)C + (size_t)grow * N + gc) = v;
                    } else {
                        const float* pv = (const float*)&v;
                        #pragma unroll
                        for (int e = 0; e < 4; ++e)
                            if (gc + e < N) ((float*)C)[(size_t)grow * N + gc + e] = pv[e];
                    }
                }
            }
        }
    }
}

// ---------------- attention
__global__ __launch_bounds__(128) void attn_kernel(const float* __restrict__ qkv,
                                                   unsigned short* __restrict__ ctx16) {
    int qi = blockIdx.x, h = blockIdx.y, b = blockIdx.z;
    const float* base = qkv + (size_t)b * SEQ * (3 * EMB);
    __shared__ float qs[DH];
    __shared__ float sc[SEQ];
    __shared__ float red;
    int t = threadIdx.x;
    if (t < DH) qs[t] = base[(size_t)qi * (3 * EMB) + h * DH + t];
    __syncthreads();
    if (t < SEQ) {
        const float* krow = base + (size_t)t * (3 * EMB) + EMB + h * DH;
        float s = 0.f;
        #pragma unroll
        for (int d = 0; d < DH; ++d) s += qs[d] * krow[d];
        sc[t] = s * 0.125f;
    }
    __syncthreads();
    if (t == 0) {
        float m = -1e30f;
        for (int j = 0; j < SEQ; ++j) m = fmaxf(m, sc[j]);
        red = m;
    }
    __syncthreads();
    float m = red;
    if (t < SEQ) sc[t] = __expf(sc[t] - m);
    __syncthreads();
    if (t == 0) {
        float s = 0.f;
        for (int j = 0; j < SEQ; ++j) s += sc[j];
        red = 1.f / s;
    }
    __syncthreads();
    float inv = red;
    if (t < DH) {
        float acc = 0.f;
        for (int j = 0; j < SEQ; ++j)
            acc += sc[j] * base[(size_t)j * (3 * EMB) + 2 * EMB + h * DH + t];
        ctx16[((size_t)b * SEQ + qi) * EMB + h * DH + t] = f2bf(acc * inv);
    }
}

// ---------------- residual + layernorm
__global__ __launch_bounds__(128) void ln_kernel(const float* __restrict__ x,
                                                 const float* __restrict__ p,
                                                 const float* __restrict__ g,
                                                 const float* __restrict__ be,
                                                 float* __restrict__ y32,
                                                 unsigned short* __restrict__ y16) {
    int row = blockIdx.x;
    int t = threadIdx.x;
    const float4 xv = ((const float4*)(x + (size_t)row * EMB))[t];
    const float4 pv = ((const float4*)(p + (size_t)row * EMB))[t];
    float v0 = xv.x + pv.x, v1 = xv.y + pv.y, v2 = xv.z + pv.z, v3 = xv.w + pv.w;
    float sum = v0 + v1 + v2 + v3;
    float sq  = v0 * v0 + v1 * v1 + v2 * v2 + v3 * v3;
    #pragma unroll
    for (int off = 32; off >= 1; off >>= 1) {
        sum += __shfl_down(sum, off);
        sq  += __shfl_down(sq,  off);
    }
    __shared__ float s0[2], s1[2];
    if ((t & 63) == 0) { s0[t >> 6] = sum; s1[t >> 6] = sq; }
    __syncthreads();
    float S = s0[0] + s0[1], Q = s1[0] + s1[1];
    float mean = S * (1.f / EMB);
    float var  = Q * (1.f / EMB) - mean * mean;
    float rstd = rsqrtf(var + 1e-5f);
    const float4 gv = ((const float4*)g)[t];
    const float4 bv = ((const float4*)be)[t];
    float4 o;
    o.x = (v0 - mean) * rstd * gv.x + bv.x;
    o.y = (v1 - mean) * rstd * gv.y + bv.y;
    o.z = (v2 - mean) * rstd * gv.z + bv.z;
    o.w = (v3 - mean) * rstd * gv.w + bv.w;
    ((float4*)(y32 + (size_t)row * EMB))[t] = o;
    ushort4 h;
    h.x = f2bf(o.x); h.y = f2bf(o.y); h.z = f2bf(o.z); h.w = f2bf(o.w);
    ((ushort4*)(y16 + (size_t)row * EMB))[t] = h;
}

extern "C" void kernel_launch(void* const* d_in, const int* in_sizes, int n_in,
                              void* d_out, int out_size, void* d_ws, size_t ws_size,
                              hipStream_t stream) {
    const float* w_emb    = (const float*)d_in[0];
    const float* table    = (const float*)d_in[1];
    const float* word_enc = (const float*)d_in[2];
    const float* Wqkv     = (const float*)d_in[3];
    const float* bqkv     = (const float*)d_in[4];
    const float* Wo       = (const float*)d_in[5];
    const float* bo       = (const float*)d_in[6];
    const float* W1       = (const float*)d_in[7];
    const float* b1       = (const float*)d_in[8];
    const float* W2       = (const float*)d_in[9];
    const float* b2       = (const float*)d_in[10];
    const float* g1       = (const float*)d_in[11];
    const float* be1      = (const float*)d_in[12];
    const float* g2       = (const float*)d_in[13];
    const float* be2      = (const float*)d_in[14];
    float* out = (float*)d_out;

    // activation buffers (both paths)
    const size_t act_bytes = (size_t)TOK * EMB * 4 * 3      // xa32, xb32, proj32
                           + (size_t)TOK * 3 * EMB * 4     // qkv32
                           + (size_t)TOK * EMB * 2 * 3     // xa16, xb16, ctx16
                           + (size_t)TOK * FF_ * 2;        // hbuf16
    const size_t wgt_bytes = (size_t)CVT_TOTAL * 2;
    const bool fast = ws_size >= act_bytes + wgt_bytes;

    char* ws = (char*)d_ws;
    unsigned short* wgt16 = nullptr;
    if (fast) { wgt16 = (unsigned short*)ws; ws += wgt_bytes; }
    float* xa32  = (float*)ws;                    ws += (size_t)TOK * EMB * 4;
    float* xb32  = (float*)ws;                    ws += (size_t)TOK * EMB * 4;
    float* qkv32 = (float*)ws;                    ws += (size_t)TOK * 3 * EMB * 4;
    float* proj32= (float*)ws;                    ws += (size_t)TOK * EMB * 4;
    unsigned short* xa16  = (unsigned short*)ws;  ws += (size_t)TOK * EMB * 2;
    unsigned short* xb16  = (unsigned short*)ws;  ws += (size_t)TOK * EMB * 2;
    unsigned short* ctx16 = (unsigned short*)ws;  ws += (size_t)TOK * EMB * 2;
    unsigned short* hbuf16= (unsigned short*)ws;  ws += (size_t)TOK * FF_ * 2;

    if (fast) cvt_kernel<<<2048, 256, 0, stream>>>(Wqkv, Wo, W1, W2, table, wgt16);

    {
        int total = BS * SEQ * EMB;
        embed_kernel<<<(total + 255) / 256, 256, 0, stream>>>(w_emb, word_enc, xa32, xa16);
    }

    if (fast) {
        const unsigned short* wq16 = wgt16;
        const unsigned short* wo16 = wgt16 + O_WO;
        const unsigned short* w116 = wgt16 + O_W1;
        const unsigned short* w216 = wgt16 + O_W2;
        const unsigned short* tab16= wgt16 + O_TAB;
        const int MR = (TOK + 63) / 64;   // 17 row tiles

        for (int l = 0; l < NL; ++l) {
            gemm3<64,64,64,0,0,0><<<dim3(MR, (3 * EMB) / 64), 256, 0, stream>>>(
                xa16, wq16 + (size_t)l * 3 * EMB * EMB, bqkv + (size_t)l * 3 * EMB,
                qkv32, TOK, 3 * EMB, EMB);
            attn_kernel<<<dim3(SEQ, NH, BS), 128, 0, stream>>>(qkv32, ctx16);
            gemm3<64,64,64,0,0,0><<<dim3(MR, EMB / 64), 256, 0, stream>>>(
                ctx16, wo16 + (size_t)l * EMB * EMB, bo + (size_t)l * EMB,
                proj32, TOK, EMB, EMB);
            ln_kernel<<<TOK, 128, 0, stream>>>(xa32, proj32, g1 + (size_t)l * EMB, be1 + (size_t)l * EMB, xb32, xb16);
            gemm3<64,64,64,1,1,0><<<dim3(MR, FF_ / 64), 256, 0, stream>>>(
                xb16, w116 + (size_t)l * FF_ * EMB, b1 + (size_t)l * FF_,
                hbuf16, TOK, FF_, EMB);
            gemm3<64,64,64,0,0,0><<<dim3(MR, EMB / 64), 256, 0, stream>>>(
                hbuf16, w216 + (size_t)l * EMB * FF_, b2 + (size_t)l * EMB,
                proj32, TOK, EMB, FF_);
            ln_kernel<<<TOK, 128, 0, stream>>>(xb32, proj32, g2 + (size_t)l * EMB, be2 + (size_t)l * EMB, xa32, xa16);
        }
        gemm3<128,128,32,0,0,1><<<dim3(TOUT / 128, (VOCAB + 127) / 128), 256, 0, stream>>>(
            xa16, tab16, nullptr, out, TOUT, VOCAB, EMB);
    } else {
        for (int l = 0; l < NL; ++l) {
            const float* Wqkv_l = Wqkv + (size_t)l * 3 * EMB * EMB;
            const float* Wo_l   = Wo   + (size_t)l * EMB * EMB;
            const float* W1_l   = W1   + (size_t)l * FF_ * EMB;
            const float* W2_l   = W2   + (size_t)l * EMB * FF_;
            gemm2<64,64,0,0,0><<<dim3((3 * EMB) / 64, (TOK + 63) / 64), 256, 0, stream>>>(
                xa16, Wqkv_l, bqkv + (size_t)l * 3 * EMB, qkv32, TOK, 3 * EMB, EMB);
            attn_kernel<<<dim3(SEQ, NH, BS), 128, 0, stream>>>(qkv32, ctx16);
            gemm2<64,64,0,0,0><<<dim3(EMB / 64, (TOK + 63) / 64), 256, 0, stream>>>(
                ctx16, Wo_l, bo + (size_t)l * EMB, proj32, TOK, EMB, EMB);
            ln_kernel<<<TOK, 128, 0, stream>>>(xa32, proj32, g1 + (size_t)l * EMB, be1 + (size_t)l * EMB, xb32, xb16);
            gemm2<64,64,1,1,0><<<dim3(FF_ / 64, (TOK + 63) / 64), 256, 0, stream>>>(
                xb16, W1_l, b1 + (size_t)l * FF_, hbuf16, TOK, FF_, EMB);
            gemm2<64,64,0,0,0><<<dim3(EMB / 64, (TOK + 63) / 64), 256, 0, stream>>>(
                hbuf16, W2_l, b2 + (size_t)l * EMB, proj32, TOK, EMB, FF_);
            ln_kernel<<<TOK, 128, 0, stream>>>(xb32, proj32, g2 + (size_t)l * EMB, be2 + (size_t)l * EMB, xa32, xa16);
        }
        gemm2<128,128,0,0,1><<<dim3((VOCAB + 127) / 128, TOUT / 128), 256, 0, stream>>>(
            xa16, table, nullptr, out, TOUT, VOCAB, EMB);
    }
}

// Round 5
// 666.888 us; speedup vs baseline: 4.0321x; 1.0591x over previous
//
#include <hip/hip_runtime.h>
#include <hip/hip_bf16.h>

// Model dims
#define EMB 512
#define NW  64
#define SEQ 65            // NW+1
#define NH  8
#define DH  64
#define NL  4
#define FF_ 2048
#define VOCAB 50257
#define BS  16
#define TOK (BS*SEQ)      // 1040
#define TOUT (BS*NW)      // 1024

typedef short short8  __attribute__((ext_vector_type(8)));   // 8 bf16 (A/B frag)
typedef unsigned short ushort8n __attribute__((ext_vector_type(8)));
typedef float f32x4   __attribute__((ext_vector_type(4)));   // C/D frag

__device__ __forceinline__ unsigned short f2bf(float f) {
    unsigned u = __float_as_uint(f);
    return (unsigned short)((u + 0x7FFF + ((u >> 16) & 1)) >> 16);  // RNE
}

template<int N> __device__ __forceinline__ void wait_vm() {
    asm volatile("s_waitcnt vmcnt(%0)" :: "n"(N) : "memory");
}

constexpr int ilog2c(int v) { return v == 32 ? 5 : v == 64 ? 6 : v == 128 ? 7 : 0; }

// ======== weight/table fp32 -> bf16 conversion (one pass, grid-stride) ========
#define SZ_WQKV (NL*3*EMB*EMB)
#define SZ_WO   (NL*EMB*EMB)
#define SZ_W1   (NL*FF_*EMB)
#define SZ_W2   (NL*EMB*FF_)
#define SZ_TAB  (VOCAB*EMB)
#define CVT_TOTAL (SZ_WQKV+SZ_WO+SZ_W1+SZ_W2+SZ_TAB)
#define O_WO   (SZ_WQKV)
#define O_W1   (O_WO+SZ_WO)
#define O_W2   (O_W1+SZ_W1)
#define O_TAB  (O_W2+SZ_W2)

__global__ void cvt_kernel(const float* __restrict__ wqkv, const float* __restrict__ wo,
                           const float* __restrict__ w1, const float* __restrict__ w2,
                           const float* __restrict__ table, unsigned short* __restrict__ dst) {
    const int U = CVT_TOTAL / 8;
    for (int u = blockIdx.x * blockDim.x + threadIdx.x; u < U; u += gridDim.x * blockDim.x) {
        size_t elem = (size_t)u * 8;
        const float* src; size_t loc = elem;
        if      (elem < O_WO)  { src = wqkv; }
        else if (elem < O_W1)  { src = wo;    loc = elem - O_WO; }
        else if (elem < O_W2)  { src = w1;    loc = elem - O_W1; }
        else if (elem < O_TAB) { src = w2;    loc = elem - O_W2; }
        else                   { src = table; loc = elem - O_TAB; }
        float4 f0 = *(const float4*)(src + loc);
        float4 f1 = *(const float4*)(src + loc + 4);
        ushort8n o;
        o[0]=f2bf(f0.x); o[1]=f2bf(f0.y); o[2]=f2bf(f0.z); o[3]=f2bf(f0.w);
        o[4]=f2bf(f1.x); o[5]=f2bf(f1.y); o[6]=f2bf(f1.z); o[7]=f2bf(f1.w);
        *(ushort8n*)(dst + elem) = o;
    }
}

// ---------------- embed
__global__ void embed_kernel(const float* __restrict__ w_emb,
                             const float* __restrict__ word_enc,
                             float* __restrict__ x32,
                             unsigned short* __restrict__ x16) {
    int idx = blockIdx.x * blockDim.x + threadIdx.x;
    const int total = BS * SEQ * EMB;
    if (idx >= total) return;
    int d = idx & (EMB - 1);
    int s = (idx >> 9) % SEQ;
    int b = idx / (SEQ * EMB);
    float we = word_enc[s * EMB + d];
    float e = (s == 0) ? 0.f : w_emb[((size_t)b * NW + (s - 1)) * EMB + d];
    float v = e + we;
    x32[idx] = v;
    x16[idx] = f2bf(v);
}

// ======== gemm3: C[M,N] = A[M,K](bf16) * B[N,K](bf16)^T + bias ========
// Both operands via global_load_lds into k-slot-major LDS (conflict-free b128 reads).
// 3-buffer depth-2 pipeline with counted vmcnt + raw s_barrier (T3/T4).
// COMPACT: logits path — 1D grid with XCD-bijective chunked swizzle + row remap.
template<int TM, int TN, int BK, int OUT_BF16, int RELU, int COMPACT>
__global__ __launch_bounds__(256) void gemm3(const unsigned short* __restrict__ A,
                                             const unsigned short* __restrict__ B,
                                             const float* __restrict__ bias,
                                             void* __restrict__ C,
                                             int M, int N, int K) {
    constexpr int LTM = ilog2c(TM);
    constexpr int LTN = ilog2c(TN);
    constexpr int FR  = TM / 32, FC = TN / 32;
    constexpr int WRH = TM / 2,  WCH = TN / 2;
    constexpr int KCH = BK / 32;
    constexpr int AI  = (TM * BK) / (8 * 256);   // gload_lds instrs for A per wave
    constexpr int BI  = (TN * BK) / (8 * 256);
    constexpr int L   = AI + BI;                 // vmem instrs per stage per wave
    constexpr int ASZ = TM * BK * 2;
    constexpr int STRIDE = (TM + TN) * BK * 2;
    __shared__ __align__(16) char smem[3 * STRIDE];

    int t = threadIdx.x;
    int w = t >> 6, l = t & 63;
    int wr = w >> 1, wc = w & 1;
    int lr = l & 15, lh = l >> 4;

    int m0, n0;
    if (COMPACT) {                 // logits: 1D grid, XCD-chunked bijective swizzle
        int bid = blockIdx.x;
        int nchunk = gridDim.x >> 3;                  // blocks per XCD (grid % 8 == 0)
        int lin = (bid & 7) * nchunk + (bid >> 3);
        m0 = (lin & 7) * TM;                          // 8 M-tiles, consecutive lin share B-panel
        n0 = (lin >> 3) * TN;
    } else {
        m0 = blockIdx.x * TM;
        n0 = blockIdx.y * TN;
    }

    f32x4 acc[FR][FC] = {};
    const int nt = K / BK;

    auto stageA = [&](int kt, int p) {
        char* dst = smem + p * STRIDE;
        #pragma unroll
        for (int i = 0; i < AI; ++i) {
            int tt = i * 256 + t;
            int row = tt & (TM - 1);
            int slot = tt >> LTM;
            int gr = m0 + row;
            if (COMPACT) gr = ((gr >> 6) * SEQ) + (gr & 63);
            else if (gr >= M) gr = M - 1;
            const unsigned short* gp = A + (size_t)gr * K + kt + slot * 8;
            __builtin_amdgcn_global_load_lds(
                (const __attribute__((address_space(1))) void*)gp,
                (__attribute__((address_space(3))) void*)(dst + (size_t)(i * 256 + w * 64) * 16),
                16, 0, 0);
        }
    };
    auto stageB = [&](int kt, int p) {
        char* dst = smem + p * STRIDE + ASZ;
        #pragma unroll
        for (int i = 0; i < BI; ++i) {
            int tt = i * 256 + t;
            int row = tt & (TN - 1);
            int slot = tt >> LTN;
            int gr = n0 + row;
            if (gr >= N) gr = N - 1;
            const unsigned short* gp = B + (size_t)gr * K + kt + slot * 8;
            __builtin_amdgcn_global_load_lds(
                (const __attribute__((address_space(1))) void*)gp,
                (__attribute__((address_space(3))) void*)(dst + (size_t)(i * 256 + w * 64) * 16),
                16, 0, 0);
        }
    };
    auto compute = [&](int p) {
        const unsigned short* as_ = (const unsigned short*)(smem + p * STRIDE);
        const unsigned short* bs_ = as_ + TM * BK;
        #pragma unroll
        for (int kk = 0; kk < KCH; ++kk) {
            short8 af[FR], bfv[FC];
            #pragma unroll
            for (int mi = 0; mi < FR; ++mi)
                af[mi] = *(const short8*)(as_ + ((size_t)(kk * 4 + lh) * TM + wr * WRH + mi * 16 + lr) * 8);
            #pragma unroll
            for (int ni = 0; ni < FC; ++ni)
                bfv[ni] = *(const short8*)(bs_ + ((size_t)(kk * 4 + lh) * TN + wc * WCH + ni * 16 + lr) * 8);
            #pragma unroll
            for (int mi = 0; mi < FR; ++mi)
                #pragma unroll
                for (int ni = 0; ni < FC; ++ni)
                    acc[mi][ni] = __builtin_amdgcn_mfma_f32_16x16x32_bf16(af[mi], bfv[ni], acc[mi][ni], 0, 0, 0);
        }
    };

    // prologue: stage tiles 0 and 1 (2L outstanding per wave)
    stageA(0, 0); stageB(0, 0);
    if (nt > 1) { stageA(BK, 1); stageB(BK, 1); }

    for (int it = 0; it < nt; ++it) {
        int p = it % 3;
        if (it + 2 < nt) {
            stageA((it + 2) * BK, (it + 2) % 3);
            stageB((it + 2) * BK, (it + 2) % 3);
            wait_vm<2 * L>();          // oldest stage (tile it) complete
        } else if (it + 1 < nt) {
            wait_vm<L>();
        } else {
            wait_vm<0>();
        }
        __builtin_amdgcn_s_barrier();          // tile it fully in LDS (all waves)
        __builtin_amdgcn_sched_barrier(0);     // keep ds_reads below the barrier
        compute(p);
        __builtin_amdgcn_sched_barrier(0);     // keep ds_reads above the end barrier
        __builtin_amdgcn_s_barrier();          // buffer p free for overwrite next iter
    }

    // ---- epilogue ----
    if (OUT_BF16) {
        #pragma unroll
        for (int ni = 0; ni < FC; ++ni) {
            int gcol = n0 + wc * WCH + ni * 16 + lr;
            if (gcol >= N) continue;
            float bv = bias ? bias[gcol] : 0.f;
            #pragma unroll
            for (int mi = 0; mi < FR; ++mi)
                #pragma unroll
                for (int r = 0; r < 4; ++r) {
                    int grow = m0 + wr * WRH + mi * 16 + lh * 4 + r;
                    if (grow >= M) continue;
                    float v = acc[mi][ni][r] + bv;
                    if (RELU) v = fmaxf(v, 0.f);
                    ((unsigned short*)C)[(size_t)grow * N + gcol] = f2bf(v);
                }
        }
    } else {
        constexpr int PAD = WCH + 4;
        constexpr int CPR = WCH / 4;
        constexpr int J   = 16 * CPR / 64;
        float* ep = (float*)smem + (size_t)w * 16 * PAD;
        float bv[FC];
        #pragma unroll
        for (int ni = 0; ni < FC; ++ni) {
            int gcol = n0 + wc * WCH + ni * 16 + lr;
            bv[ni] = (bias && gcol < N) ? bias[gcol] : 0.f;
        }
        #pragma unroll
        for (int mi = 0; mi < FR; ++mi) {
            asm volatile("s_waitcnt lgkmcnt(0)" ::: "memory");
            #pragma unroll
            for (int ni = 0; ni < FC; ++ni)
                #pragma unroll
                for (int r = 0; r < 4; ++r) {
                    float v = acc[mi][ni][r] + bv[ni];
                    if (RELU) v = fmaxf(v, 0.f);
                    ep[(lh * 4 + r) * PAD + ni * 16 + lr] = v;
                }
            asm volatile("s_waitcnt lgkmcnt(0)" ::: "memory");
            __builtin_amdgcn_sched_barrier(0);
            #pragma unroll
            for (int j = 0; j < J; ++j) {
                int f4  = j * 64 + l;
                int row = f4 / CPR;
                int c4  = f4 % CPR;
                int grow = m0 + wr * WRH + mi * 16 + row;
                int gc   = n0 + wc * WCH + c4 * 4;
                if (grow < M) {
                    float4 v = *(const float4*)(ep + row * PAD + c4 * 4);
                    if (gc + 3 < N) {
                        *(float4*)((float*)C + (size_t)grow * N + gc) = v;
                    } else {
                        const float* pv = (const float*)&v;
                        #pragma unroll
                        for (int e = 0; e < 4; ++e)
                            if (gc + e < N) ((float*)C)[(size_t)grow * N + gc + e] = pv[e];
                    }
                }
            }
        }
    }
}

// ======== gemm2 (fallback: B fp32 inline-converted, 2-buffer) ========
template<int TM, int TN, int OUT_BF16, int RELU, int COMPACT>
__global__ __launch_bounds__(256) void gemm2(const unsigned short* __restrict__ A,
                                             const float* __restrict__ B,
                                             const float* __restrict__ bias,
                                             void* __restrict__ C,
                                             int M, int N, int K) {
    constexpr int LTM = (TM == 128) ? 7 : 6;
    constexpr int FR  = TM / 32, FC = TN / 32;
    constexpr int WRH = TM / 2,  WCH = TN / 2;
    constexpr int AI  = TM / 64;
    constexpr int TPR = 256 / TN;
    constexpr int SPT = 4 / TPR;
    constexpr int STRIDE = (TM + TN) * 64;
    __shared__ __align__(16) char smem[2 * STRIDE];

    int t = threadIdx.x;
    int w = t >> 6, l = t & 63;
    int wr = w >> 1, wc = w & 1;
    int lr = l & 15, lh = l >> 4;
    int m0 = blockIdx.y * TM, n0 = blockIdx.x * TN;

    int br = t / TPR, bh = t % TPR;
    int gbr = n0 + br; if (gbr >= N) gbr = N - 1;
    const float* bbase = B + (size_t)gbr * K + bh * (SPT * 8);

    f32x4  acc[FR][FC] = {};
    float4 breg[TN / 32];
    const int nt = K >> 5;

    auto stageA = [&](int kt, int p) {
        char* dst = smem + p * STRIDE;
        #pragma unroll
        for (int i = 0; i < AI; ++i) {
            int tt   = i * 256 + t;
            int row  = tt & (TM - 1);
            int slot = tt >> LTM;
            int gr   = m0 + row;
            if (COMPACT) gr = ((gr >> 6) * SEQ) + (gr & 63);
            else if (gr >= M) gr = M - 1;
            const unsigned short* gp = A + (size_t)gr * K + kt + slot * 8;
            __builtin_amdgcn_global_load_lds(
                (const __attribute__((address_space(1))) void*)gp,
                (__attribute__((address_space(3))) void*)(dst + (size_t)(i * 256 + w * 64) * 16),
                16, 0, 0);
        }
    };
    auto loadB = [&](int kt) {
        const float* bp = bbase + kt;
        #pragma unroll
        for (int j = 0; j < TN / 32; ++j) breg[j] = *(const float4*)(bp + j * 4);
    };
    auto writeB = [&](int p) {
        unsigned short* bs = (unsigned short*)(smem + p * STRIDE + TM * 64);
        #pragma unroll
        for (int s = 0; s < SPT; ++s) {
            ushort8n u;
            #pragma unroll
            for (int e = 0; e < 8; ++e) {
                float f = ((const float*)&breg[s * 2 + (e >> 2)])[e & 3];
                u[e] = f2bf(f);
            }
            int slot = bh * SPT + s;
            *(ushort8n*)(bs + ((size_t)slot * TN + br) * 8) = u;
        }
    };
    auto compute = [&](int p) {
        const unsigned short* as_ = (const unsigned short*)(smem + p * STRIDE);
        const unsigned short* bs_ = as_ + TM * 32;
        short8 af[FR], bfv[FC];
        #pragma unroll
        for (int mi = 0; mi < FR; ++mi)
            af[mi] = *(const short8*)(as_ + ((size_t)lh * TM + wr * WRH + mi * 16 + lr) * 8);
        #pragma unroll
        for (int ni = 0; ni < FC; ++ni)
            bfv[ni] = *(const short8*)(bs_ + ((size_t)lh * TN + wc * WCH + ni * 16 + lr) * 8);
        #pragma unroll
        for (int mi = 0; mi < FR; ++mi)
            #pragma unroll
            for (int ni = 0; ni < FC; ++ni)
                acc[mi][ni] = __builtin_amdgcn_mfma_f32_16x16x32_bf16(af[mi], bfv[ni], acc[mi][ni], 0, 0, 0);
    };

    stageA(0, 0); loadB(0); writeB(0);
    __syncthreads();
    for (int it = 0; it < nt; ++it) {
        int p = it & 1;
        if (it + 1 < nt) { stageA((it + 1) << 5, 1 - p); loadB((it + 1) << 5); }
        compute(p);
        if (it + 1 < nt) writeB(1 - p);
        __syncthreads();
    }

    if (OUT_BF16) {
        #pragma unroll
        for (int ni = 0; ni < FC; ++ni) {
            int gcol = n0 + wc * WCH + ni * 16 + lr;
            if (gcol >= N) continue;
            float bv = bias ? bias[gcol] : 0.f;
            #pragma unroll
            for (int mi = 0; mi < FR; ++mi)
                #pragma unroll
                for (int r = 0; r < 4; ++r) {
                    int grow = m0 + wr * WRH + mi * 16 + lh * 4 + r;
                    if (grow >= M) continue;
                    float v = acc[mi][ni][r] + bv;
                    if (RELU) v = fmaxf(v, 0.f);
                    ((unsigned short*)C)[(size_t)grow * N + gcol] = f2bf(v);
                }
        }
    } else {
        constexpr int PAD = WCH + 4;
        constexpr int CPR = WCH / 4;
        constexpr int J   = 16 * CPR / 64;
        float* ep = (float*)smem + (size_t)w * 16 * PAD;
        float bv[FC];
        #pragma unroll
        for (int ni = 0; ni < FC; ++ni) {
            int gcol = n0 + wc * WCH + ni * 16 + lr;
            bv[ni] = (bias && gcol < N) ? bias[gcol] : 0.f;
        }
        #pragma unroll
        for (int mi = 0; mi < FR; ++mi) {
            asm volatile("s_waitcnt lgkmcnt(0)" ::: "memory");
            #pragma unroll
            for (int ni = 0; ni < FC; ++ni)
                #pragma unroll
                for (int r = 0; r < 4; ++r) {
                    float v = acc[mi][ni][r] + bv[ni];
                    if (RELU) v = fmaxf(v, 0.f);
                    ep[(lh * 4 + r) * PAD + ni * 16 + lr] = v;
                }
            asm volatile("s_waitcnt lgkmcnt(0)" ::: "memory");
            __builtin_amdgcn_sched_barrier(0);
            #pragma unroll
            for (int j = 0; j < J; ++j) {
                int f4  = j * 64 + l;
                int row = f4 / CPR;
                int c4  = f4 % CPR;
                int grow = m0 + wr * WRH + mi * 16 + row;
                int gc   = n0 + wc * WCH + c4 * 4;
                if (grow < M) {
                    float4 v = *(const float4*)(ep + row * PAD + c4 * 4);
                    if (gc + 3 < N) {
                        *(float4*)((float*)C + (size_t)grow * N + gc) = v;
                    } else {
                        const float* pv = (const float*)&v;
                        #pragma unroll
                        for (int e = 0; e < 4; ++e)
                            if (gc + e < N) ((float*)C)[(size_t)grow * N + gc + e] = pv[e];
                    }
                }
            }
        }
    }
}

// ---------------- attention
__global__ __launch_bounds__(128) void attn_kernel(const float* __restrict__ qkv,
                                                   unsigned short* __restrict__ ctx16) {
    int qi = blockIdx.x, h = blockIdx.y, b = blockIdx.z;
    const float* base = qkv + (size_t)b * SEQ * (3 * EMB);
    __shared__ float qs[DH];
    __shared__ float sc[SEQ];
    __shared__ float red;
    int t = threadIdx.x;
    if (t < DH) qs[t] = base[(size_t)qi * (3 * EMB) + h * DH + t];
    __syncthreads();
    if (t < SEQ) {
        const float* krow = base + (size_t)t * (3 * EMB) + EMB + h * DH;
        float s = 0.f;
        #pragma unroll
        for (int d = 0; d < DH; ++d) s += qs[d] * krow[d];
        sc[t] = s * 0.125f;
    }
    __syncthreads();
    if (t == 0) {
        float m = -1e30f;
        for (int j = 0; j < SEQ; ++j) m = fmaxf(m, sc[j]);
        red = m;
    }
    __syncthreads();
    float m = red;
    if (t < SEQ) sc[t] = __expf(sc[t] - m);
    __syncthreads();
    if (t == 0) {
        float s = 0.f;
        for (int j = 0; j < SEQ; ++j) s += sc[j];
        red = 1.f / s;
    }
    __syncthreads();
    float inv = red;
    if (t < DH) {
        float acc = 0.f;
        for (int j = 0; j < SEQ; ++j)
            acc += sc[j] * base[(size_t)j * (3 * EMB) + 2 * EMB + h * DH + t];
        ctx16[((size_t)b * SEQ + qi) * EMB + h * DH + t] = f2bf(acc * inv);
    }
}

// ---------------- residual + layernorm
__global__ __launch_bounds__(128) void ln_kernel(const float* __restrict__ x,
                                                 const float* __restrict__ p,
                                                 const float* __restrict__ g,
                                                 const float* __restrict__ be,
                                                 float* __restrict__ y32,
                                                 unsigned short* __restrict__ y16) {
    int row = blockIdx.x;
    int t = threadIdx.x;
    const float4 xv = ((const float4*)(x + (size_t)row * EMB))[t];
    const float4 pv = ((const float4*)(p + (size_t)row * EMB))[t];
    float v0 = xv.x + pv.x, v1 = xv.y + pv.y, v2 = xv.z + pv.z, v3 = xv.w + pv.w;
    float sum = v0 + v1 + v2 + v3;
    float sq  = v0 * v0 + v1 * v1 + v2 * v2 + v3 * v3;
    #pragma unroll
    for (int off = 32; off >= 1; off >>= 1) {
        sum += __shfl_down(sum, off);
        sq  += __shfl_down(sq,  off);
    }
    __shared__ float s0[2], s1[2];
    if ((t & 63) == 0) { s0[t >> 6] = sum; s1[t >> 6] = sq; }
    __syncthreads();
    float S = s0[0] + s0[1], Q = s1[0] + s1[1];
    float mean = S * (1.f / EMB);
    float var  = Q * (1.f / EMB) - mean * mean;
    float rstd = rsqrtf(var + 1e-5f);
    const float4 gv = ((const float4*)g)[t];
    const float4 bv = ((const float4*)be)[t];
    float4 o;
    o.x = (v0 - mean) * rstd * gv.x + bv.x;
    o.y = (v1 - mean) * rstd * gv.y + bv.y;
    o.z = (v2 - mean) * rstd * gv.z + bv.z;
    o.w = (v3 - mean) * rstd * gv.w + bv.w;
    ((float4*)(y32 + (size_t)row * EMB))[t] = o;
    ushort4 h;
    h.x = f2bf(o.x); h.y = f2bf(o.y); h.z = f2bf(o.z); h.w = f2bf(o.w);
    ((ushort4*)(y16 + (size_t)row * EMB))[t] = h;
}

extern "C" void kernel_launch(void* const* d_in, const int* in_sizes, int n_in,
                              void* d_out, int out_size, void* d_ws, size_t ws_size,
                              hipStream_t stream) {
    const float* w_emb    = (const float*)d_in[0];
    const float* table    = (const float*)d_in[1];
    const float* word_enc = (const float*)d_in[2];
    const float* Wqkv     = (const float*)d_in[3];
    const float* bqkv     = (const float*)d_in[4];
    const float* Wo       = (const float*)d_in[5];
    const float* bo       = (const float*)d_in[6];
    const float* W1       = (const float*)d_in[7];
    const float* b1       = (const float*)d_in[8];
    const float* W2       = (const float*)d_in[9];
    const float* b2       = (const float*)d_in[10];
    const float* g1       = (const float*)d_in[11];
    const float* be1      = (const float*)d_in[12];
    const float* g2       = (const float*)d_in[13];
    const float* be2      = (const float*)d_in[14];
    float* out = (float*)d_out;

    const size_t act_bytes = (size_t)TOK * EMB * 4 * 3
                           + (size_t)TOK * 3 * EMB * 4
                           + (size_t)TOK * EMB * 2 * 3
                           + (size_t)TOK * FF_ * 2;
    const size_t wgt_bytes = (size_t)CVT_TOTAL * 2;
    const bool fast = ws_size >= act_bytes + wgt_bytes;

    char* ws = (char*)d_ws;
    unsigned short* wgt16 = nullptr;
    if (fast) { wgt16 = (unsigned short*)ws; ws += wgt_bytes; }
    float* xa32  = (float*)ws;                    ws += (size_t)TOK * EMB * 4;
    float* xb32  = (float*)ws;                    ws += (size_t)TOK * EMB * 4;
    float* qkv32 = (float*)ws;                    ws += (size_t)TOK * 3 * EMB * 4;
    float* proj32= (float*)ws;                    ws += (size_t)TOK * EMB * 4;
    unsigned short* xa16  = (unsigned short*)ws;  ws += (size_t)TOK * EMB * 2;
    unsigned short* xb16  = (unsigned short*)ws;  ws += (size_t)TOK * EMB * 2;
    unsigned short* ctx16 = (unsigned short*)ws;  ws += (size_t)TOK * EMB * 2;
    unsigned short* hbuf16= (unsigned short*)ws;  ws += (size_t)TOK * FF_ * 2;

    if (fast) cvt_kernel<<<2048, 256, 0, stream>>>(Wqkv, Wo, W1, W2, table, wgt16);

    {
        int total = BS * SEQ * EMB;
        embed_kernel<<<(total + 255) / 256, 256, 0, stream>>>(w_emb, word_enc, xa32, xa16);
    }

    if (fast) {
        const unsigned short* wq16 = wgt16;
        const unsigned short* wo16 = wgt16 + O_WO;
        const unsigned short* w116 = wgt16 + O_W1;
        const unsigned short* w216 = wgt16 + O_W2;
        const unsigned short* tab16= wgt16 + O_TAB;
        const int MR = (TOK + 63) / 64;   // 17 row tiles

        for (int l = 0; l < NL; ++l) {
            gemm3<64,64,64,0,0,0><<<dim3(MR, (3 * EMB) / 64), 256, 0, stream>>>(
                xa16, wq16 + (size_t)l * 3 * EMB * EMB, bqkv + (size_t)l * 3 * EMB,
                qkv32, TOK, 3 * EMB, EMB);
            attn_kernel<<<dim3(SEQ, NH, BS), 128, 0, stream>>>(qkv32, ctx16);
            gemm3<64,32,64,0,0,0><<<dim3(MR, EMB / 32), 256, 0, stream>>>(
                ctx16, wo16 + (size_t)l * EMB * EMB, bo + (size_t)l * EMB,
                proj32, TOK, EMB, EMB);
            ln_kernel<<<TOK, 128, 0, stream>>>(xa32, proj32, g1 + (size_t)l * EMB, be1 + (size_t)l * EMB, xb32, xb16);
            gemm3<64,64,64,1,1,0><<<dim3(MR, FF_ / 64), 256, 0, stream>>>(
                xb16, w116 + (size_t)l * FF_ * EMB, b1 + (size_t)l * FF_,
                hbuf16, TOK, FF_, EMB);
            gemm3<64,32,64,0,0,0><<<dim3(MR, EMB / 32), 256, 0, stream>>>(
                hbuf16, w216 + (size_t)l * EMB * FF_, b2 + (size_t)l * EMB,
                proj32, TOK, EMB, FF_);
            ln_kernel<<<TOK, 128, 0, stream>>>(xb32, proj32, g2 + (size_t)l * EMB, be2 + (size_t)l * EMB, xa32, xa16);
        }
        // logits: 1D grid = 8 M-tiles * 393 N-tiles = 3144 (divisible by 8 -> bijective swizzle)
        gemm3<128,128,32,0,0,1><<<dim3((TOUT / 128) * ((VOCAB + 127) / 128)), 256, 0, stream>>>(
            xa16, tab16, nullptr, out, TOUT, VOCAB, EMB);
    } else {
        for (int l = 0; l < NL; ++l) {
            const float* Wqkv_l = Wqkv + (size_t)l * 3 * EMB * EMB;
            const float* Wo_l   = Wo   + (size_t)l * EMB * EMB;
            const float* W1_l   = W1   + (size_t)l * FF_ * EMB;
            const float* W2_l   = W2   + (size_t)l * EMB * FF_;
            gemm2<64,64,0,0,0><<<dim3((3 * EMB) / 64, (TOK + 63) / 64), 256, 0, stream>>>(
                xa16, Wqkv_l, bqkv + (size_t)l * 3 * EMB, qkv32, TOK, 3 * EMB, EMB);
            attn_kernel<<<dim3(SEQ, NH, BS), 128, 0, stream>>>(qkv32, ctx16);
            gemm2<64,64,0,0,0><<<dim3(EMB / 64, (TOK + 63) / 64), 256, 0, stream>>>(
                ctx16, Wo_l, bo + (size_t)l * EMB, proj32, TOK, EMB, EMB);
            ln_kernel<<<TOK, 128, 0, stream>>>(xa32, proj32, g1 + (size_t)l * EMB, be1 + (size_t)l * EMB, xb32, xb16);
            gemm2<64,64,1,1,0><<<dim3(FF_ / 64, (TOK + 63) / 64), 256, 0, stream>>>(
                xb16, W1_l, b1 + (size_t)l * FF_, hbuf16, TOK, FF_, EMB);
            gemm2<64,64,0,0,0><<<dim3(EMB / 64, (TOK + 63) / 64), 256, 0, stream>>>(
                hbuf16, W2_l, b2 + (size_t)l * EMB, proj32, TOK, EMB, FF_);
            ln_kernel<<<TOK, 128, 0, stream>>>(xb32, proj32, g2 + (size_t)l * EMB, be2 + (size_t)l * EMB, xa32, xa16);
        }
        gemm2<128,128,0,0,1><<<dim3((VOCAB + 127) / 128, TOUT / 128), 256, 0, stream>>>(
            xa16, table, nullptr, out, TOUT, VOCAB, EMB);
    }
}